// Round 1
// baseline (87064.813 us; speedup 1.0000x reference)
//
#include <hip/hip_runtime.h>

#define DEVI __device__ __forceinline__

namespace {

constexpr int T_N   = 2000;
constexpr int DIN   = 120;
constexpr int H     = 320;
constexpr int H2    = 640;
constexpr int H4    = 1280;
constexpr int NLAY  = 4;
constexpr int V     = 10000;
constexpr int BEAM  = 4;
constexpr int STEPS = 200;

// encoder scan config: 8 workgroups per direction, weights in VGPRs
constexpr int EWG = 8;
constexpr int ETH = 256;
constexpr int RWG = H4 / EWG;   // 160 rows per WG
constexpr int RPT = 5;          // rows per thread (32 row-groups x 5)
constexpr int KSL = H / 8;      // 40 k per thread

// decoder config
constexpr int DWG = 64, DTH = 256;
constexpr int NCH = 16;                    // attention t-chunks
constexpr int TCH = T_N / NCH;             // 125
constexpr int LCH = 48;                    // logits chunks
constexpr int LROWS = (V + LCH - 1) / LCH; // 209

// ---- workspace layout (float offsets) ----
constexpr size_t O_CTRL   = 0;                         // 256 ints (barrier counters, padded)
constexpr size_t O_CST    = 256;                       // c state [4][320]
constexpr size_t O_HST    = O_CST + BEAM * H;          // h state [4][320]
constexpr size_t O_SEQ    = O_HST + BEAM * H;          // int [2][4][200]
constexpr size_t O_SCORES = O_SEQ + 2 * BEAM * STEPS;  // [4]
constexpr size_t N_ZERO   = O_SCORES + 8;              // zeroed region end
constexpr size_t O_SPROJ  = N_ZERO;                    // [4][640]
constexpr size_t O_PDEN   = O_SPROJ + BEAM * H2;       // [4][16]
constexpr size_t O_PEXP   = O_PDEN + BEAM * NCH;       // [48][4]
constexpr size_t O_PTV    = O_PEXP + LCH * BEAM;       // [48][4][4]
constexpr size_t O_PTI    = O_PTV + LCH * BEAM * 4;    // int [48][4][4]
constexpr size_t O_GVEC   = O_PTI + LCH * BEAM * 4;    // [4][640]
constexpr size_t O_PRE    = O_GVEC + BEAM * H2;        // [4][320]
constexpr size_t O_ABUF   = O_PRE + BEAM * H;          // [4][1280]
constexpr size_t O_PG     = O_ABUF + BEAM * H4;        // [4][16][640]
constexpr size_t O_GBUF   = O_PG + (size_t)BEAM * NCH * H2;  // [2 dir][2 pp][1280]
constexpr size_t O_C1     = O_GBUF + 4 * H4;
constexpr size_t O_C2     = O_C1 + H4;
constexpr size_t O_MMAT   = O_C2 + H4;                 // [1280][320]
constexpr size_t O_HPROJ  = O_MMAT + (size_t)H4 * H;   // [2000][640]
constexpr size_t O_HBA    = O_HPROJ + (size_t)T_N * H2;
constexpr size_t O_HBB    = O_HBA + (size_t)T_N * H2;
constexpr size_t O_XP     = O_HBB + (size_t)T_N * H2;  // [2][2000][1280]

DEVI float wredsum1(float v) {
#pragma unroll
  for (int m = 32; m > 0; m >>= 1) v += __shfl_xor(v, m, 64);
  return v;
}

template <int N>
DEVI void wredsumN(float* a) {
#pragma unroll
  for (int m = 32; m > 0; m >>= 1) {
#pragma unroll
    for (int i = 0; i < N; ++i) a[i] += __shfl_xor(a[i], m, 64);
  }
}

DEVI float sg(float x) { return 0.5f * tanhf(0.5f * x) + 0.5f; }  // sigmoid (jax form)

DEVI float fast_tanh(float x) {  // overflow-safe, used only in attention feed-forward
  float ax = fabsf(x);
  float z = __expf(-2.f * ax);
  float t = 1.f - 2.f * z / (1.f + z);
  return x < 0.f ? -t : t;
}

DEVI void insert4(float* bv, int* bi, float v, int ix) {
#pragma unroll
  for (int s = 0; s < 4; ++s) {
    if (v > bv[s] || (v == bv[s] && ix < bi[s])) {
      float tv = bv[s]; int ti = bi[s];
      bv[s] = v; bi[s] = ix; v = tv; ix = ti;
    }
  }
}

// ======================= tiled fp32 GEMM =======================
// C[M][N] = A[M][K] @ op(B) + bias ; BT: B is (N,K) row-major (compute A@B^T)
//                                   !BT: B is (K,N) row-major (compute A@B)
template <bool BT>
__global__ __launch_bounds__(256) void gemm64(
    const float* __restrict__ A, const float* __restrict__ B,
    const float* __restrict__ bias, float* __restrict__ C,
    int M, int N, int K, size_t sB, size_t sBias, size_t sC) {
  __shared__ float As[16][68];
  __shared__ float Bs[16][68];
  const int tid = threadIdx.x;
  const int tx = tid & 15, ty = tid >> 4;
  const int n0 = blockIdx.x * 64, m0 = blockIdx.y * 64;
  const float* Bz = B + (size_t)blockIdx.z * sB;
  float acc[4][4] = {};
  for (int kk = 0; kk < K; kk += 16) {
    {  // stage A tile (64m x 16k), transpose to As[k][m]
      const int m = tid >> 2, kq = (tid & 3) << 2;
      float4 v = make_float4(0.f, 0.f, 0.f, 0.f);
      if (m0 + m < M) {
        if (kk + kq + 3 < K) {
          v = *(const float4*)(A + (size_t)(m0 + m) * K + kk + kq);
        } else {
          float t0 = (kk + kq + 0 < K) ? A[(size_t)(m0 + m) * K + kk + kq + 0] : 0.f;
          float t1 = (kk + kq + 1 < K) ? A[(size_t)(m0 + m) * K + kk + kq + 1] : 0.f;
          float t2 = (kk + kq + 2 < K) ? A[(size_t)(m0 + m) * K + kk + kq + 2] : 0.f;
          float t3 = (kk + kq + 3 < K) ? A[(size_t)(m0 + m) * K + kk + kq + 3] : 0.f;
          v = make_float4(t0, t1, t2, t3);
        }
      }
      As[kq + 0][m] = v.x; As[kq + 1][m] = v.y; As[kq + 2][m] = v.z; As[kq + 3][m] = v.w;
    }
    if (BT) {
      const int n = tid >> 2, kq = (tid & 3) << 2;
      float4 v = make_float4(0.f, 0.f, 0.f, 0.f);
      if (kk + kq + 3 < K) {
        v = *(const float4*)(Bz + (size_t)(n0 + n) * K + kk + kq);
      } else {
        float t0 = (kk + kq + 0 < K) ? Bz[(size_t)(n0 + n) * K + kk + kq + 0] : 0.f;
        float t1 = (kk + kq + 1 < K) ? Bz[(size_t)(n0 + n) * K + kk + kq + 1] : 0.f;
        float t2 = (kk + kq + 2 < K) ? Bz[(size_t)(n0 + n) * K + kk + kq + 2] : 0.f;
        float t3 = (kk + kq + 3 < K) ? Bz[(size_t)(n0 + n) * K + kk + kq + 3] : 0.f;
        v = make_float4(t0, t1, t2, t3);
      }
      Bs[kq + 0][n] = v.x; Bs[kq + 1][n] = v.y; Bs[kq + 2][n] = v.z; Bs[kq + 3][n] = v.w;
    } else {
      const int kr = tid >> 4, nq = (tid & 15) << 2;
      float4 v = make_float4(0.f, 0.f, 0.f, 0.f);
      if (kk + kr < K) v = *(const float4*)(Bz + (size_t)(kk + kr) * N + n0 + nq);
      *(float4*)&Bs[kr][nq] = v;
    }
    __syncthreads();
#pragma unroll
    for (int k = 0; k < 16; ++k) {
      const float4 a = *(const float4*)&As[k][ty << 2];
      const float4 b = *(const float4*)&Bs[k][tx << 2];
      acc[0][0] += a.x * b.x; acc[0][1] += a.x * b.y; acc[0][2] += a.x * b.z; acc[0][3] += a.x * b.w;
      acc[1][0] += a.y * b.x; acc[1][1] += a.y * b.y; acc[1][2] += a.y * b.z; acc[1][3] += a.y * b.w;
      acc[2][0] += a.z * b.x; acc[2][1] += a.z * b.y; acc[2][2] += a.z * b.z; acc[2][3] += a.z * b.w;
      acc[3][0] += a.w * b.x; acc[3][1] += a.w * b.y; acc[3][2] += a.w * b.z; acc[3][3] += a.w * b.w;
    }
    __syncthreads();
  }
#pragma unroll
  for (int i = 0; i < 4; ++i) {
    const int m = m0 + (ty << 2) + i;
    if (m < M) {
#pragma unroll
      for (int j = 0; j < 4; ++j) {
        const int n = n0 + (tx << 2) + j;
        float v = acc[i][j];
        if (bias) v += bias[blockIdx.z * sBias + n];
        C[(size_t)blockIdx.z * sC + (size_t)m * N + n] = v;
      }
    }
  }
}

// c1[j] = sum_v ys_w[j,v]*yy_b[v] ; c2[j] = sum_v ys_w[j,v]
__global__ __launch_bounds__(256) void c1c2k(
    const float* __restrict__ ys_w, const float* __restrict__ yy_b,
    float* __restrict__ c1, float* __restrict__ c2) {
  const int j = blockIdx.x;
  const float* row = ys_w + (size_t)j * V;
  float s1 = 0.f, s2 = 0.f;
  for (int v = threadIdx.x; v < V; v += 256) {
    const float w = row[v];
    s1 += w * yy_b[v];
    s2 += w;
  }
  s1 = wredsum1(s1); s2 = wredsum1(s2);
  __shared__ float r1[4], r2[4];
  if ((threadIdx.x & 63) == 0) { r1[threadIdx.x >> 6] = s1; r2[threadIdx.x >> 6] = s2; }
  __syncthreads();
  if (threadIdx.x == 0) {
    c1[j] = (r1[0] + r1[1]) + (r1[2] + r1[3]);
    c2[j] = (r2[0] + r2[1]) + (r2[2] + r2[3]);
  }
}

// ======================= BiLSTM recurrent scan =======================
// grid = 16 WGs: 8 per direction. whh held in VGPRs; per-step cross-WG barrier
// per direction (monotonic counter, double-buffered gbuf).
__global__ __launch_bounds__(ETH, 1) void lstm_scan(
    const float* __restrict__ whh,    // [2][H4][H]
    const float* __restrict__ xproj,  // [2][T][H4]
    float* __restrict__ hpack,        // [T][H2]
    float* __restrict__ gbuf,         // [2][2][H4]
    unsigned* __restrict__ cnt)       // per-dir counters (stride 16 ints)
{
  const int wg = blockIdx.x;
  const int dir = wg / EWG, wl = wg % EWG;
  const int tid = threadIdx.x;
  const int rg = tid >> 3, cg = tid & 7;
  const float* Wd = whh + (size_t)dir * H4 * H;
  const float* xp = xproj + (size_t)dir * T_N * H4;
  unsigned* mycnt = cnt + dir * 16;

  float w[RPT][KSL];
#pragma unroll
  for (int i = 0; i < RPT; ++i) {
    const int r = wl * RWG + rg * RPT + i;
    const float* wr = Wd + (size_t)r * H + cg * KSL;
#pragma unroll
    for (int j = 0; j < KSL; ++j) w[i][j] = wr[j];
  }

  __shared__ float hlds[H];
  __shared__ float part[RWG][8];
  float c0 = 0.f, c1 = 0.f;
  for (int e = tid; e < H; e += ETH) hlds[e] = 0.f;
  __syncthreads();

  for (int t = 0; t < T_N; ++t) {
    const int tt = dir ? (T_N - 1 - t) : t;
    float acc[RPT] = {};
#pragma unroll
    for (int j4 = 0; j4 < KSL / 4; ++j4) {
      const float4 hv = *(const float4*)&hlds[cg * KSL + j4 * 4];
#pragma unroll
      for (int i = 0; i < RPT; ++i)
        acc[i] += w[i][j4 * 4 + 0] * hv.x + w[i][j4 * 4 + 1] * hv.y +
                  w[i][j4 * 4 + 2] * hv.z + w[i][j4 * 4 + 3] * hv.w;
    }
#pragma unroll
    for (int i = 0; i < RPT; ++i) part[rg * RPT + i][cg] = acc[i];
    __syncthreads();
    float* gslot = gbuf + (size_t)(dir * 2 + (t & 1)) * H4;
    if (tid < RWG) {
      const float4 p0 = *(const float4*)&part[tid][0];
      const float4 p1 = *(const float4*)&part[tid][4];
      const float s = ((p0.x + p0.y) + (p0.z + p0.w)) + ((p1.x + p1.y) + (p1.z + p1.w));
      const int r = wl * RWG + tid;
      gslot[r] = s + xp[(size_t)tt * H4 + r];
    }
    __threadfence();
    __syncthreads();
    if (tid == 0) {
      __hip_atomic_fetch_add(mycnt, 1u, __ATOMIC_ACQ_REL, __HIP_MEMORY_SCOPE_AGENT);
      const unsigned tgt = (unsigned)EWG * (unsigned)(t + 1);
      while (__hip_atomic_load(mycnt, __ATOMIC_ACQUIRE, __HIP_MEMORY_SCOPE_AGENT) < tgt) {}
    }
    __syncthreads();
    // gate nonlinearity + state update (replicated in every WG of the direction)
    {
      const float gi = gslot[tid], gf = gslot[tid + H], gc = gslot[tid + 2 * H], go = gslot[tid + 3 * H];
      c0 = sg(gf) * c0 + sg(gi) * tanhf(gc);
      const float h = sg(go) * tanhf(c0);
      hlds[tid] = h;
      if (wl == 0) hpack[(size_t)tt * H2 + dir * H + tid] = h;
    }
    if (tid < H - ETH) {
      const int j = ETH + tid;
      const float gi = gslot[j], gf = gslot[j + H], gc = gslot[j + 2 * H], go = gslot[j + 3 * H];
      c1 = sg(gf) * c1 + sg(gi) * tanhf(gc);
      const float h = sg(go) * tanhf(c1);
      hlds[j] = h;
      if (wl == 0) hpack[(size_t)tt * H2 + dir * H + j] = h;
    }
    __syncthreads();
  }
}

// ======================= persistent beam-search decoder =======================
struct DecArgs {
  const float* atts_w; const float* attw_w;
  const float* sy_w; const float* gy_w; const float* gy_b;
  const float* yy_w; const float* yy_b;
  const float* gs_b; const float* ys_b;
  const float* ss_w; const float* gs_w;
  const float* hpack; const float* hproj; const float* Mm; const float* c1; const float* c2;
  float* cst; float* hst; float* scores;
  float* sproj; float* pden; float* pexp; float* ptv;
  float* gvec; float* pre; float* abuf; float* pg;
  int* pti; int* seq;
  unsigned* cnt;
  float* out;
};

__global__ __launch_bounds__(DTH, 1) void decoder(DecArgs A) {
  const int wg = blockIdx.x, tid = threadIdx.x;
  const int wid = tid >> 6, lane = tid & 63;
  __shared__ float sm[8192];
  __shared__ float cand_val[16];
  __shared__ int cand_tok[16];
  __shared__ int parent_s[BEAM];
  __shared__ int tok_s[BEAM];
  unsigned bar_t = 0;

  auto BAR = [&]() {
    bar_t += DWG;
    __threadfence();
    __syncthreads();
    if (tid == 0) {
      __hip_atomic_fetch_add(A.cnt, 1u, __ATOMIC_ACQ_REL, __HIP_MEMORY_SCOPE_AGENT);
      while (__hip_atomic_load(A.cnt, __ATOMIC_ACQUIRE, __HIP_MEMORY_SCOPE_AGENT) < bar_t) {}
    }
    __syncthreads();
  };

  if (wg == 0 && tid < BEAM) A.scores[tid] = (tid == 0) ? 0.f : -1e9f;

  for (int step = 0; step < STEPS; ++step) {
    // ---- S1: sproj = s @ atts_w^T  (wave-per-dot, 10 dots/wave) ----
    {
      const int gw = wg * 4 + wid;
      float pr[10];
      const float* hb0 = A.hst;
#pragma unroll
      for (int q = 0; q < 10; ++q) {
        const int o = gw * 10 + q;
        const int b = o / H2, k = o - b * H2;
        const float* ar = A.atts_w + (size_t)k * H;
        const float* hb = hb0 + b * H;
        float p = 0.f;
#pragma unroll
        for (int mi = 0; mi < H / 64; ++mi) p += hb[lane + mi * 64] * ar[lane + mi * 64];
        pr[q] = p;
      }
      wredsumN<10>(pr);
      if (lane == 0) {
#pragma unroll
        for (int q = 0; q < 10; ++q) A.sproj[gw * 10 + q] = pr[q];
      }
    }
    BAR();
    // ---- S2: attention scores + exp + chunk numerator/denominator ----
    {
      const int b = wg & 3, ch = wg >> 2;
      float* sp = sm;
      float* aw = sm + H2;
      float* el = sm + 2 * H2;  // 125
      for (int e = tid; e < H2; e += DTH) { sp[e] = A.sproj[b * H2 + e]; aw[e] = A.attw_w[e]; }
      __syncthreads();
      for (int base = wid; base < TCH; base += 8) {
        const bool v2 = (base + 4) < TCH;
        const int t1 = ch * TCH + base;
        const int t2 = ch * TCH + (v2 ? base + 4 : base);
        const float* hp1 = A.hproj + (size_t)t1 * H2;
        const float* hp2 = A.hproj + (size_t)t2 * H2;
        float pr[2] = {0.f, 0.f};
#pragma unroll
        for (int q = 0; q < H2 / 64; ++q) {
          const int k = lane + q * 64;
          pr[0] += fast_tanh(sp[k] + hp1[k]) * aw[k];
          pr[1] += fast_tanh(sp[k] + hp2[k]) * aw[k];
        }
        wredsumN<2>(pr);
        if (lane == 0) {
          el[base] = __expf(pr[0]);
          if (v2) el[base + 4] = __expf(pr[1]);
        }
      }
      __syncthreads();
      if (wid == 0) {
        float p = (lane < TCH) ? el[lane] : 0.f;
        if (lane + 64 < TCH) p += el[lane + 64];
        p = wredsum1(p);
        if (lane == 0) A.pden[b * NCH + ch] = p;
      }
      // numerator partial: sum_t e[t]*hpack[t][k], k owned per thread
      float a0 = 0.f, a1 = 0.f, a2 = 0.f;
      const float* hb = A.hpack + (size_t)ch * TCH * H2;
#pragma unroll 5
      for (int ti = 0; ti < TCH; ++ti) {
        const float ev = el[ti];
        const float* hr = hb + (size_t)ti * H2;
        a0 += ev * hr[tid];
        a1 += ev * hr[tid + 256];
        if (tid < H2 - 512) a2 += ev * hr[tid + 512];
      }
      float* pgp = A.pg + (size_t)(b * NCH + ch) * H2;
      pgp[tid] = a0;
      pgp[tid + 256] = a1;
      if (tid < H2 - 512) pgp[tid + 512] = a2;
    }
    BAR();
    // ---- S3: reduce g, then pre = tanh(s@sy^T + g@gy^T + gy_b) ----
    {
      const int b = wg >> 4, r0 = (wg & 15) * 20;
      float* gl = sm;  // 640
      float den = 0.f;
#pragma unroll
      for (int c = 0; c < NCH; ++c) den += A.pden[b * NCH + c];
      for (int k = tid; k < H2; k += DTH) {
        float s = 0.f;
#pragma unroll
        for (int c = 0; c < NCH; ++c) s += A.pg[(size_t)(b * NCH + c) * H2 + k];
        s = s / den;
        gl[k] = s;
        if ((wg & 15) == 0) A.gvec[b * H2 + k] = s;
      }
      __syncthreads();
      float pr[5];
      const float* hb = A.hst + b * H;
#pragma unroll
      for (int q = 0; q < 5; ++q) {
        const int j = r0 + wid * 5 + q;
        const float* syr = A.sy_w + (size_t)j * H;
        const float* gyr = A.gy_w + (size_t)j * H2;
        float p = 0.f;
#pragma unroll
        for (int mi = 0; mi < H / 64; ++mi) p += hb[lane + mi * 64] * syr[lane + mi * 64];
#pragma unroll
        for (int ki = 0; ki < H2 / 64; ++ki) p += gl[lane + ki * 64] * gyr[lane + ki * 64];
        pr[q] = p;
      }
      wredsumN<5>(pr);
      if (lane == 0) {
#pragma unroll
        for (int q = 0; q < 5; ++q) {
          const int j = r0 + wid * 5 + q;
          A.pre[b * H + j] = tanhf(pr[q] + A.gy_b[j]);
        }
      }
    }
    BAR();
    // ---- S5: gates-partial A (WGs 0..15) || logits + top4 + expsum (WGs 16..63) ----
    if (wg < 16) {
      const int b = wg >> 2, j0 = (wg & 3) * 320;
      float* sb = sm;
      float* gb = sm + H;
      float* pb = sm + H + H2;
      for (int e = tid; e < H; e += DTH) { sb[e] = A.hst[b * H + e]; pb[e] = A.pre[b * H + e]; }
      for (int e = tid; e < H2; e += DTH) gb[e] = A.gvec[b * H2 + e];
      __syncthreads();
      for (int g4 = 0; g4 < 20; ++g4) {
        float pr[4];
#pragma unroll
        for (int u = 0; u < 4; ++u) {
          const int j = j0 + wid * 80 + g4 * 4 + u;
          const float* ssr = A.ss_w + (size_t)j * H;
          const float* gsr = A.gs_w + (size_t)j * H2;
          const float* mr = A.Mm + (size_t)j * H;
          float p = 0.f;
#pragma unroll
          for (int mi = 0; mi < H / 64; ++mi) {
            const int m = lane + mi * 64;
            p += sb[m] * ssr[m] + pb[m] * mr[m];
          }
#pragma unroll
          for (int ki = 0; ki < H2 / 64; ++ki) {
            const int k = lane + ki * 64;
            p += gb[k] * gsr[k];
          }
          pr[u] = p;
        }
        wredsumN<4>(pr);
        if (lane == 0) {
#pragma unroll
          for (int u = 0; u < 4; ++u) {
            const int j = j0 + wid * 80 + g4 * 4 + u;
            A.abuf[b * H4 + j] = pr[u] + A.gs_b[j] + A.ys_b[j] + A.c1[j];
          }
        }
      }
    } else {
      const int ch = wg - 16;
      const int v0 = ch * LROWS;
      const int cn_ = (V - v0 < LROWS) ? (V - v0) : LROWS;
      float* pl = sm;             // 1280: pre for 4 beams
      float* wsum = sm + 1536;    // [4 waves][4 beams]
      float* wtv = sm + 1552;     // [4][4][4]
      int* wti = (int*)(sm + 1616);
      for (int e = tid; e < BEAM * H; e += DTH) pl[e] = A.pre[e];
      __syncthreads();
      float lg[4];
      const bool valid = tid < cn_;
      const int v = v0 + tid;
      if (valid) {
        const float* yr = A.yy_w + (size_t)v * H;
        float l0 = 0.f, l1 = 0.f, l2 = 0.f, l3 = 0.f;
#pragma unroll 4
        for (int m = 0; m < H; m += 4) {
          const float4 yv = *(const float4*)(yr + m);
          l0 += yv.x * pl[m] + yv.y * pl[m + 1] + yv.z * pl[m + 2] + yv.w * pl[m + 3];
          l1 += yv.x * pl[H + m] + yv.y * pl[H + m + 1] + yv.z * pl[H + m + 2] + yv.w * pl[H + m + 3];
          l2 += yv.x * pl[2 * H + m] + yv.y * pl[2 * H + m + 1] + yv.z * pl[2 * H + m + 2] + yv.w * pl[2 * H + m + 3];
          l3 += yv.x * pl[3 * H + m] + yv.y * pl[3 * H + m + 1] + yv.z * pl[3 * H + m + 2] + yv.w * pl[3 * H + m + 3];
        }
        const float bb = A.yy_b[v];
        lg[0] = l0 + bb; lg[1] = l1 + bb; lg[2] = l2 + bb; lg[3] = l3 + bb;
      } else {
        lg[0] = lg[1] = lg[2] = lg[3] = -3.402823466e38f;
      }
      {
        float es[4];
#pragma unroll
        for (int b = 0; b < 4; ++b) es[b] = valid ? __expf(lg[b]) : 0.f;
        wredsumN<4>(es);
        if (lane == 0) {
#pragma unroll
          for (int b = 0; b < 4; ++b) wsum[wid * 4 + b] = es[b];
        }
      }
      {  // per-wave top-4 per beam, 4 beams' shfl chains interleaved
        float tv[4]; int tix[4];
#pragma unroll
        for (int b = 0; b < 4; ++b) { tv[b] = lg[b]; tix[b] = v; }
#pragma unroll
        for (int it = 0; it < 4; ++it) {
          float mv[4]; int mi_[4];
#pragma unroll
          for (int b = 0; b < 4; ++b) { mv[b] = tv[b]; mi_[b] = tix[b]; }
#pragma unroll
          for (int mm = 32; mm > 0; mm >>= 1) {
#pragma unroll
            for (int b = 0; b < 4; ++b) {
              const float ov = __shfl_xor(mv[b], mm, 64);
              const int oi = __shfl_xor(mi_[b], mm, 64);
              if (ov > mv[b] || (ov == mv[b] && oi < mi_[b])) { mv[b] = ov; mi_[b] = oi; }
            }
          }
          if (lane == 0) {
#pragma unroll
            for (int b = 0; b < 4; ++b) { wtv[(wid * 4 + b) * 4 + it] = mv[b]; wti[(wid * 4 + b) * 4 + it] = mi_[b]; }
          }
#pragma unroll
          for (int b = 0; b < 4; ++b)
            if (tix[b] == mi_[b]) tv[b] = -3.402823466e38f;
        }
      }
      __syncthreads();
      if (tid < BEAM) {
        const int b = tid;
        A.pexp[ch * BEAM + b] = (wsum[b] + wsum[4 + b]) + (wsum[8 + b] + wsum[12 + b]);
        float bv[4] = {-3.402823466e38f, -3.402823466e38f, -3.402823466e38f, -3.402823466e38f};
        int bi[4] = {0x7fffffff, 0x7fffffff, 0x7fffffff, 0x7fffffff};
        for (int wv = 0; wv < 4; ++wv)
          for (int q = 0; q < 4; ++q) insert4(bv, bi, wtv[(wv * 4 + b) * 4 + q], wti[(wv * 4 + b) * 4 + q]);
#pragma unroll
        for (int q = 0; q < 4; ++q) { A.ptv[(ch * BEAM + b) * 4 + q] = bv[q]; A.pti[(ch * BEAM + b) * 4 + q] = bi[q]; }
      }
    }
    BAR();
    // ---- S6: serial combine (1 WG): lse, global top-4, gates, cell, beam gather ----
    if (wg == 0) {
      float* lse_s = sm + 7680;
      if (tid < LCH * BEAM) {
        const int b = tid & 3, w = tid >> 2;
        sm[b * LCH + w] = A.pexp[w * BEAM + b];
      }
      __syncthreads();
      if (tid < BEAM) {
        float s_ = 0.f;
        for (int w = 0; w < LCH; ++w) s_ += sm[tid * LCH + w];
        lse_s[tid] = logf(s_);
      }
      __syncthreads();
      if (tid < BEAM) {
        const int b = tid;
        float bv[4] = {-3.402823466e38f, -3.402823466e38f, -3.402823466e38f, -3.402823466e38f};
        int bi[4] = {0x7fffffff, 0x7fffffff, 0x7fffffff, 0x7fffffff};
        for (int w = 0; w < LCH; ++w)
          for (int q = 0; q < 4; ++q) insert4(bv, bi, A.ptv[(w * BEAM + b) * 4 + q], A.pti[(w * BEAM + b) * 4 + q]);
        const float sc = A.scores[b];
#pragma unroll
        for (int q = 0; q < 4; ++q) { cand_val[b * 4 + q] = sc + (bv[q] - lse_s[b]); cand_tok[b * 4 + q] = bi[q]; }
      }
      __syncthreads();
      if (tid == 0) {
        float bv[4] = {-3.402823466e38f, -3.402823466e38f, -3.402823466e38f, -3.402823466e38f};
        int bf[4] = {0x7fffffff, 0x7fffffff, 0x7fffffff, 0x7fffffff};
        for (int f = 0; f < 16; ++f) insert4(bv, bf, cand_val[f], f);
#pragma unroll
        for (int q = 0; q < 4; ++q) {
          parent_s[q] = bf[q] >> 2;
          tok_s[q] = cand_tok[bf[q]];
          A.scores[q] = bv[q];
        }
      }
      __syncthreads();
      for (int e = tid; e < BEAM * H4; e += DTH) {
        const int b = e / H4, j = e - b * H4;
        sm[e] = tanhf(A.abuf[e] - lse_s[b] * A.c2[j]);
      }
      __syncthreads();
      float* cn2 = sm + 5120;
      float* hn2 = sm + 6400;
      for (int e = tid; e < BEAM * H; e += DTH) {
        const int b = e / H, jj = e - b * H;
        const float gi = sm[b * H4 + jj], gf = sm[b * H4 + H + jj];
        const float gc = sm[b * H4 + 2 * H + jj], go = sm[b * H4 + 3 * H + jj];
        const float ig = 0.5f * tanhf(0.5f * gi) + 0.5f;
        const float fg = 0.5f * tanhf(0.5f * gf) + 0.5f;
        const float og = 0.5f * tanhf(0.5f * go) + 0.5f;
        const float cv = fg * A.cst[e] + ig * tanhf(gc);
        cn2[e] = cv;
        hn2[e] = og * tanhf(cv);
      }
      __syncthreads();
      for (int e = tid; e < BEAM * H; e += DTH) {
        const int b = e / H, jj = e - b * H;
        const int p = parent_s[b];
        A.cst[e] = cn2[p * H + jj];
        A.hst[e] = hn2[p * H + jj];
      }
      {
        int* src = A.seq + (step & 1) * (BEAM * STEPS);
        int* dst = A.seq + ((step & 1) ^ 1) * (BEAM * STEPS);
        for (int e = tid; e < BEAM * STEPS; e += DTH) {
          const int b = e / STEPS, ts = e - b * STEPS;
          dst[e] = (ts == step) ? tok_s[b] : src[parent_s[b] * STEPS + ts];
        }
      }
    }
    BAR();
  }
  if (wg == 0) {
    for (int e = tid; e < BEAM * STEPS; e += DTH) A.out[e] = (float)A.seq[e];
    if (tid < BEAM) A.out[BEAM * STEPS + tid] = A.scores[tid];
  }
}

}  // namespace

extern "C" void kernel_launch(void* const* d_in, const int* in_sizes, int n_in,
                              void* d_out, int out_size, void* d_ws, size_t ws_size,
                              hipStream_t stream) {
  (void)in_sizes; (void)n_in; (void)out_size; (void)ws_size;
  const float* data   = (const float*)d_in[0];
  const float* wih0   = (const float*)d_in[1];
  const float* whh0   = (const float*)d_in[2];
  const float* b0     = (const float*)d_in[3];
  const float* wihL   = (const float*)d_in[4];
  const float* whhL   = (const float*)d_in[5];
  const float* bL     = (const float*)d_in[6];
  const float* atts_w = (const float*)d_in[7];
  const float* atth_w = (const float*)d_in[8];
  const float* atth_b = (const float*)d_in[9];
  const float* attw_w = (const float*)d_in[10];
  const float* sy_w   = (const float*)d_in[11];
  const float* gy_w   = (const float*)d_in[12];
  const float* gy_b   = (const float*)d_in[13];
  const float* yy_w   = (const float*)d_in[14];
  const float* yy_b   = (const float*)d_in[15];
  const float* ss_w   = (const float*)d_in[16];
  const float* gs_w   = (const float*)d_in[17];
  const float* gs_b   = (const float*)d_in[18];
  const float* ys_w   = (const float*)d_in[19];
  const float* ys_b   = (const float*)d_in[20];

  float* W = (float*)d_ws;
  unsigned* cnt = (unsigned*)d_ws;
  (void)hipMemsetAsync(d_ws, 0, N_ZERO * sizeof(float), stream);

  // Mmat = ys_w @ yy_w, plus folded constants c1, c2
  {
    dim3 g(H / 64, H4 / 64, 1);
    gemm64<false><<<g, 256, 0, stream>>>(ys_w, yy_w, nullptr, W + O_MMAT, H4, H, V, 0, 0, 0);
  }
  c1c2k<<<H4, 256, 0, stream>>>(ys_w, yy_b, W + O_C1, W + O_C2);

  float* xp = W + O_XP;
  float* hA = W + O_HBA;
  float* hB = W + O_HBB;

  // ---- encoder ----
  {
    dim3 g(H4 / 64, (T_N + 63) / 64, 2);
    gemm64<true><<<g, 256, 0, stream>>>(data, wih0, b0, xp, T_N, H4, DIN,
                                        (size_t)H4 * DIN, H4, (size_t)T_N * H4);
  }
  lstm_scan<<<2 * EWG, ETH, 0, stream>>>(whh0, xp, hA, W + O_GBUF, cnt);
  for (int l = 1; l < NLAY; ++l) {
    const float* inb = (l & 1) ? hA : hB;
    float* outb = (l & 1) ? hB : hA;
    dim3 g(H4 / 64, (T_N + 63) / 64, 2);
    gemm64<true><<<g, 256, 0, stream>>>(inb, wihL + (size_t)(l - 1) * 2 * H4 * H2,
                                        bL + (size_t)(l - 1) * 2 * H4, xp, T_N, H4, H2,
                                        (size_t)H4 * H2, H4, (size_t)T_N * H4);
    lstm_scan<<<2 * EWG, ETH, 0, stream>>>(whhL + (size_t)(l - 1) * 2 * H4 * H, xp, outb,
                                           W + O_GBUF, cnt + l * 32);
  }
  const float* hfin = hB;  // layer 3 output

  // hproj = hpack @ atth_w^T + atth_b
  {
    dim3 g(H2 / 64, (T_N + 63) / 64, 1);
    gemm64<true><<<g, 256, 0, stream>>>(hfin, atth_w, atth_b, W + O_HPROJ, T_N, H2, H2, 0, 0, 0);
  }

  // ---- decoder ----
  DecArgs da;
  da.atts_w = atts_w; da.attw_w = attw_w;
  da.sy_w = sy_w; da.gy_w = gy_w; da.gy_b = gy_b;
  da.yy_w = yy_w; da.yy_b = yy_b;
  da.gs_b = gs_b; da.ys_b = ys_b;
  da.ss_w = ss_w; da.gs_w = gs_w;
  da.hpack = hfin; da.hproj = W + O_HPROJ; da.Mm = W + O_MMAT; da.c1 = W + O_C1; da.c2 = W + O_C2;
  da.cst = W + O_CST; da.hst = W + O_HST; da.scores = W + O_SCORES;
  da.sproj = W + O_SPROJ; da.pden = W + O_PDEN; da.pexp = W + O_PEXP; da.ptv = W + O_PTV;
  da.gvec = W + O_GVEC; da.pre = W + O_PRE; da.abuf = W + O_ABUF; da.pg = W + O_PG;
  da.pti = (int*)(W + O_PTI); da.seq = (int*)(W + O_SEQ);
  da.cnt = cnt + 160;
  da.out = (float*)d_out;
  decoder<<<DWG, DTH, 0, stream>>>(da);
}

// Round 3
// 62733.600 us; speedup vs baseline: 1.3878x; 1.3878x over previous
//
#include <hip/hip_runtime.h>

#define DEVI __device__ __forceinline__

namespace {

constexpr int T_N   = 2000;
constexpr int DIN   = 120;
constexpr int H     = 320;
constexpr int H2    = 640;
constexpr int H4    = 1280;
constexpr int NLAY  = 4;
constexpr int V     = 10000;
constexpr int BEAM  = 4;
constexpr int STEPS = 200;

// encoder scan config: 8 workgroups per direction, weights in VGPRs
constexpr int EWG = 8;
constexpr int ETH = 256;
constexpr int RWG = H4 / EWG;   // 160 rows per WG
constexpr int RPT = 5;          // rows per thread (32 row-groups x 5)
constexpr int KSL = H / 8;      // 40 k per thread

// decoder config
constexpr int DWG = 64, DTH = 256;
constexpr int NCH = 16;                    // attention t-chunks
constexpr int TCH = T_N / NCH;             // 125
constexpr int LCH = 48;                    // logits chunks
constexpr int LROWS = (V + LCH - 1) / LCH; // 209

// ---- workspace layout (float offsets) ----
constexpr size_t O_CTRL   = 0;                         // 256 ints (barrier counters)
constexpr size_t N_ZERO   = 256;                       // zeroed region end
constexpr size_t O_SPROJ  = N_ZERO;                    // [4][640]
constexpr size_t O_PDEN   = O_SPROJ + BEAM * H2;       // [4][16]
constexpr size_t O_PEXP   = O_PDEN + BEAM * NCH;       // [48][4]
constexpr size_t O_PTV    = O_PEXP + LCH * BEAM;       // [48][4][4]
constexpr size_t O_PTI    = O_PTV + LCH * BEAM * 4;    // int [48][4][4]
constexpr size_t O_GVEC   = O_PTI + LCH * BEAM * 4;    // [4][640]
constexpr size_t O_PRE    = O_GVEC + BEAM * H2;        // [4][320]
constexpr size_t O_ABUF   = O_PRE + BEAM * H;          // [4][1280]
constexpr size_t O_PG     = O_ABUF + BEAM * H4;        // [4][16][640]
constexpr size_t O_GBUF   = O_PG + (size_t)BEAM * NCH * H2;  // [2 dir][2 pp][1280]
constexpr size_t O_C1     = O_GBUF + 4 * H4;
constexpr size_t O_C2     = O_C1 + H4;
constexpr size_t O_MMAT   = O_C2 + H4;                 // [1280][320]
constexpr size_t O_HPROJ  = O_MMAT + (size_t)H4 * H;   // [2000][640]
constexpr size_t O_HBA    = O_HPROJ + (size_t)T_N * H2;
constexpr size_t O_HBB    = O_HBA + (size_t)T_N * H2;
constexpr size_t O_XP     = O_HBB + (size_t)T_N * H2;  // [2][2000][1280]

// ---- coherent (cache-bypassing, no-fence) accessors for cross-WG data ----
DEVI float cload(const float* p) {
  return __hip_atomic_load((float*)p, __ATOMIC_RELAXED, __HIP_MEMORY_SCOPE_SYSTEM);
}
DEVI int cloadi(const int* p) {
  return __hip_atomic_load((int*)p, __ATOMIC_RELAXED, __HIP_MEMORY_SCOPE_SYSTEM);
}
DEVI void cstore(float* p, float v) {
  __hip_atomic_store(p, v, __ATOMIC_RELAXED, __HIP_MEMORY_SCOPE_SYSTEM);
}
DEVI void cstorei(int* p, int v) {
  __hip_atomic_store(p, v, __ATOMIC_RELAXED, __HIP_MEMORY_SCOPE_SYSTEM);
}
DEVI unsigned cloadu(const unsigned* p) {
  return __hip_atomic_load((unsigned*)p, __ATOMIC_RELAXED, __HIP_MEMORY_SCOPE_SYSTEM);
}

DEVI float wredsum1(float v) {
#pragma unroll
  for (int m = 32; m > 0; m >>= 1) v += __shfl_xor(v, m, 64);
  return v;
}

template <int N>
DEVI void wredsumN(float* a) {
#pragma unroll
  for (int m = 32; m > 0; m >>= 1) {
#pragma unroll
    for (int i = 0; i < N; ++i) a[i] += __shfl_xor(a[i], m, 64);
  }
}

DEVI float sg(float x) { return 0.5f * tanhf(0.5f * x) + 0.5f; }  // sigmoid (jax form)

DEVI float fast_tanh(float x) {  // overflow-safe, used only in attention feed-forward
  float ax = fabsf(x);
  float z = __expf(-2.f * ax);
  float t = 1.f - 2.f * z / (1.f + z);
  return x < 0.f ? -t : t;
}

DEVI void insert4(float* bv, int* bi, float v, int ix) {
#pragma unroll
  for (int s = 0; s < 4; ++s) {
    if (v > bv[s] || (v == bv[s] && ix < bi[s])) {
      float tv = bv[s]; int ti = bi[s];
      bv[s] = v; bi[s] = ix; v = tv; ix = ti;
    }
  }
}

// ======================= tiled fp32 GEMM =======================
template <bool BT>
__global__ __launch_bounds__(256) void gemm64(
    const float* __restrict__ A, const float* __restrict__ B,
    const float* __restrict__ bias, float* __restrict__ C,
    int M, int N, int K, size_t sB, size_t sBias, size_t sC) {
  __shared__ float As[16][68];
  __shared__ float Bs[16][68];
  const int tid = threadIdx.x;
  const int tx = tid & 15, ty = tid >> 4;
  const int n0 = blockIdx.x * 64, m0 = blockIdx.y * 64;
  const float* Bz = B + (size_t)blockIdx.z * sB;
  float acc[4][4] = {};
  for (int kk = 0; kk < K; kk += 16) {
    {
      const int m = tid >> 2, kq = (tid & 3) << 2;
      float4 v = make_float4(0.f, 0.f, 0.f, 0.f);
      if (m0 + m < M) {
        if (kk + kq + 3 < K) {
          v = *(const float4*)(A + (size_t)(m0 + m) * K + kk + kq);
        } else {
          float t0 = (kk + kq + 0 < K) ? A[(size_t)(m0 + m) * K + kk + kq + 0] : 0.f;
          float t1 = (kk + kq + 1 < K) ? A[(size_t)(m0 + m) * K + kk + kq + 1] : 0.f;
          float t2 = (kk + kq + 2 < K) ? A[(size_t)(m0 + m) * K + kk + kq + 2] : 0.f;
          float t3 = (kk + kq + 3 < K) ? A[(size_t)(m0 + m) * K + kk + kq + 3] : 0.f;
          v = make_float4(t0, t1, t2, t3);
        }
      }
      As[kq + 0][m] = v.x; As[kq + 1][m] = v.y; As[kq + 2][m] = v.z; As[kq + 3][m] = v.w;
    }
    if (BT) {
      const int n = tid >> 2, kq = (tid & 3) << 2;
      float4 v = make_float4(0.f, 0.f, 0.f, 0.f);
      if (kk + kq + 3 < K) {
        v = *(const float4*)(Bz + (size_t)(n0 + n) * K + kk + kq);
      } else {
        float t0 = (kk + kq + 0 < K) ? Bz[(size_t)(n0 + n) * K + kk + kq + 0] : 0.f;
        float t1 = (kk + kq + 1 < K) ? Bz[(size_t)(n0 + n) * K + kk + kq + 1] : 0.f;
        float t2 = (kk + kq + 2 < K) ? Bz[(size_t)(n0 + n) * K + kk + kq + 2] : 0.f;
        float t3 = (kk + kq + 3 < K) ? Bz[(size_t)(n0 + n) * K + kk + kq + 3] : 0.f;
        v = make_float4(t0, t1, t2, t3);
      }
      Bs[kq + 0][n] = v.x; Bs[kq + 1][n] = v.y; Bs[kq + 2][n] = v.z; Bs[kq + 3][n] = v.w;
    } else {
      const int kr = tid >> 4, nq = (tid & 15) << 2;
      float4 v = make_float4(0.f, 0.f, 0.f, 0.f);
      if (kk + kr < K) v = *(const float4*)(Bz + (size_t)(kk + kr) * N + n0 + nq);
      *(float4*)&Bs[kr][nq] = v;
    }
    __syncthreads();
#pragma unroll
    for (int k = 0; k < 16; ++k) {
      const float4 a = *(const float4*)&As[k][ty << 2];
      const float4 b = *(const float4*)&Bs[k][tx << 2];
      acc[0][0] += a.x * b.x; acc[0][1] += a.x * b.y; acc[0][2] += a.x * b.z; acc[0][3] += a.x * b.w;
      acc[1][0] += a.y * b.x; acc[1][1] += a.y * b.y; acc[1][2] += a.y * b.z; acc[1][3] += a.y * b.w;
      acc[2][0] += a.z * b.x; acc[2][1] += a.z * b.y; acc[2][2] += a.z * b.z; acc[2][3] += a.z * b.w;
      acc[3][0] += a.w * b.x; acc[3][1] += a.w * b.y; acc[3][2] += a.w * b.z; acc[3][3] += a.w * b.w;
    }
    __syncthreads();
  }
#pragma unroll
  for (int i = 0; i < 4; ++i) {
    const int m = m0 + (ty << 2) + i;
    if (m < M) {
#pragma unroll
      for (int j = 0; j < 4; ++j) {
        const int n = n0 + (tx << 2) + j;
        float v = acc[i][j];
        if (bias) v += bias[blockIdx.z * sBias + n];
        C[(size_t)blockIdx.z * sC + (size_t)m * N + n] = v;
      }
    }
  }
}

// c1[j] = sum_v ys_w[j,v]*yy_b[v] ; c2[j] = sum_v ys_w[j,v]
__global__ __launch_bounds__(256) void c1c2k(
    const float* __restrict__ ys_w, const float* __restrict__ yy_b,
    float* __restrict__ c1, float* __restrict__ c2) {
  const int j = blockIdx.x;
  const float* row = ys_w + (size_t)j * V;
  float s1 = 0.f, s2 = 0.f;
  for (int v = threadIdx.x; v < V; v += 256) {
    const float w = row[v];
    s1 += w * yy_b[v];
    s2 += w;
  }
  s1 = wredsum1(s1); s2 = wredsum1(s2);
  __shared__ float r1[4], r2[4];
  if ((threadIdx.x & 63) == 0) { r1[threadIdx.x >> 6] = s1; r2[threadIdx.x >> 6] = s2; }
  __syncthreads();
  if (threadIdx.x == 0) {
    c1[j] = (r1[0] + r1[1]) + (r1[2] + r1[3]);
    c2[j] = (r2[0] + r2[1]) + (r2[2] + r2[3]);
  }
}

// ======================= BiLSTM recurrent scan =======================
// 16 WGs: 8 per direction. whh in VGPRs; arrival = relaxed RMW, poll = relaxed
// coherent LOAD (no cache maintenance, no RMW storms); gslot via coherent ld/st.
__global__ __launch_bounds__(ETH, 1) void lstm_scan(
    const float* __restrict__ whh,    // [2][H4][H]
    const float* __restrict__ xproj,  // [2][T][H4]
    float* __restrict__ hpack,        // [T][H2]
    float* __restrict__ gbuf,         // [2][2][1280]
    unsigned* __restrict__ cnt)       // per-dir counters (stride 16 ints)
{
  const int wg = blockIdx.x;
  const int dir = wg / EWG, wl = wg % EWG;
  const int tid = threadIdx.x;
  const int rg = tid >> 3, cg = tid & 7;
  const float* Wd = whh + (size_t)dir * H4 * H;
  const float* xp = xproj + (size_t)dir * T_N * H4;
  unsigned* mycnt = cnt + dir * 16;

  float w[RPT][KSL];
#pragma unroll
  for (int i = 0; i < RPT; ++i) {
    const int r = wl * RWG + rg * RPT + i;
    const float* wr = Wd + (size_t)r * H + cg * KSL;
#pragma unroll
    for (int j = 0; j < KSL; ++j) w[i][j] = wr[j];
  }

  __shared__ float hlds[H];
  __shared__ float part[RWG][8];
  float c0 = 0.f, c1 = 0.f;
  for (int e = tid; e < H; e += ETH) hlds[e] = 0.f;
  __syncthreads();

  for (int t = 0; t < T_N; ++t) {
    const int tt = dir ? (T_N - 1 - t) : t;
    float acc[RPT] = {};
#pragma unroll
    for (int j4 = 0; j4 < KSL / 4; ++j4) {
      const float4 hv = *(const float4*)&hlds[cg * KSL + j4 * 4];
#pragma unroll
      for (int i = 0; i < RPT; ++i)
        acc[i] += w[i][j4 * 4 + 0] * hv.x + w[i][j4 * 4 + 1] * hv.y +
                  w[i][j4 * 4 + 2] * hv.z + w[i][j4 * 4 + 3] * hv.w;
    }
#pragma unroll
    for (int i = 0; i < RPT; ++i) part[rg * RPT + i][cg] = acc[i];
    __syncthreads();
    float* gslot = gbuf + (size_t)(dir * 2 + (t & 1)) * H4;
    if (tid < RWG) {
      const float4 p0 = *(const float4*)&part[tid][0];
      const float4 p1 = *(const float4*)&part[tid][4];
      const float s = ((p0.x + p0.y) + (p0.z + p0.w)) + ((p1.x + p1.y) + (p1.z + p1.w));
      const int r = wl * RWG + tid;
      cstore(&gslot[r], s + xp[(size_t)tt * H4 + r]);
    }
    __syncthreads();  // drains vmcnt (coherent stores ack'd at coherence point)
    if (tid == 0) {
      __hip_atomic_fetch_add(mycnt, 1u, __ATOMIC_RELAXED, __HIP_MEMORY_SCOPE_AGENT);
      const unsigned tgt = (unsigned)EWG * (unsigned)(t + 1);
      while (cloadu(mycnt) < tgt) __builtin_amdgcn_s_sleep(1);
    }
    __syncthreads();
    // gate nonlinearity + state update (replicated in every WG of the direction)
    {
      const float gi = cload(&gslot[tid]);
      const float gf = cload(&gslot[tid + H]);
      const float gc = cload(&gslot[tid + 2 * H]);
      const float go = cload(&gslot[tid + 3 * H]);
      c0 = sg(gf) * c0 + sg(gi) * tanhf(gc);
      const float h = sg(go) * tanhf(c0);
      hlds[tid] = h;
      if (wl == 0) hpack[(size_t)tt * H2 + dir * H + tid] = h;
    }
    if (tid < H - ETH) {
      const int j = ETH + tid;
      const float gi = cload(&gslot[j]);
      const float gf = cload(&gslot[j + H]);
      const float gc = cload(&gslot[j + 2 * H]);
      const float go = cload(&gslot[j + 3 * H]);
      c1 = sg(gf) * c1 + sg(gi) * tanhf(c1 * 0.f + gc);
      const float h = sg(go) * tanhf(c1);
      hlds[j] = h;
      if (wl == 0) hpack[(size_t)tt * H2 + dir * H + j] = h;
    }
    __syncthreads();
  }
}

// ======================= persistent beam-search decoder =======================
struct DecArgs {
  const float* atts_w; const float* attw_w;
  const float* sy_w; const float* gy_w; const float* gy_b;
  const float* yy_w; const float* yy_b;
  const float* gs_b; const float* ys_b;
  const float* ss_w; const float* gs_w;
  const float* hpack; const float* hproj; const float* Mm; const float* c1; const float* c2;
  float* sproj; float* pden; float* pexp; float* ptv;
  float* gvec; float* pre; float* abuf; float* pg;
  int* pti;
  unsigned* cnt;
  float* out;
};

__global__ __launch_bounds__(DTH, 1) void decoder(DecArgs A) {
  const int wg = blockIdx.x, tid = threadIdx.x;
  const int wid = tid >> 6, lane = tid & 63;
  __shared__ float sm[8192];
  __shared__ float cstL[BEAM * H];   // beam cell state (persistent, replicated per WG)
  __shared__ float hstL[BEAM * H];   // beam hidden state
  __shared__ int   seqL[2][BEAM * STEPS];
  __shared__ float scl[BEAM];
  __shared__ float lse_sm[BEAM];
  __shared__ float cand_val[16];
  __shared__ int cand_tok[16];
  __shared__ int parent_s[BEAM];
  __shared__ int tok_s[BEAM];
  unsigned bar_t = 0;

  auto BAR = [&]() {
    bar_t += DWG;
    __syncthreads();  // hipcc emits s_waitcnt vmcnt(0) before s_barrier -> stores ack'd
    if (tid == 0) {
      __hip_atomic_fetch_add(A.cnt, 1u, __ATOMIC_RELAXED, __HIP_MEMORY_SCOPE_AGENT);
      while (cloadu(A.cnt) < bar_t) __builtin_amdgcn_s_sleep(1);
    }
    __syncthreads();
  };

  for (int e = tid; e < BEAM * H; e += DTH) { cstL[e] = 0.f; hstL[e] = 0.f; }
  if (tid < BEAM) scl[tid] = (tid == 0) ? 0.f : -1e9f;
  __syncthreads();

  for (int step = 0; step < STEPS; ++step) {
    // ---- S1: sproj = s @ atts_w^T  (hst is WG-local LDS) ----
    {
      const int gw = wg * 4 + wid;
      float pr[10];
#pragma unroll
      for (int q = 0; q < 10; ++q) {
        const int o = gw * 10 + q;
        const int b = o / H2, k = o - b * H2;
        const float* ar = A.atts_w + (size_t)k * H;
        const float* hb = hstL + b * H;
        float p = 0.f;
#pragma unroll
        for (int mi = 0; mi < H / 64; ++mi) p += hb[lane + mi * 64] * ar[lane + mi * 64];
        pr[q] = p;
      }
      wredsumN<10>(pr);
      if (lane == 0) {
#pragma unroll
        for (int q = 0; q < 10; ++q) cstore(&A.sproj[gw * 10 + q], pr[q]);
      }
    }
    BAR();
    // ---- S2: attention scores + exp + chunk numerator/denominator ----
    {
      // XCD-affinity mapping: the 4 beams sharing chunk ch land on the same XCD
      const int b = (wg >> 3) & 3, ch = (wg & 7) | ((wg >> 5) << 3);
      float* sp = sm;
      float* aw = sm + H2;
      float* el = sm + 2 * H2;  // 125
      for (int e = tid; e < H2; e += DTH) { sp[e] = cload(&A.sproj[b * H2 + e]); aw[e] = A.attw_w[e]; }
      __syncthreads();
      for (int base = wid; base < TCH; base += 8) {
        const bool v2 = (base + 4) < TCH;
        const int t1 = ch * TCH + base;
        const int t2 = ch * TCH + (v2 ? base + 4 : base);
        const float* hp1 = A.hproj + (size_t)t1 * H2;
        const float* hp2 = A.hproj + (size_t)t2 * H2;
        float pr[2] = {0.f, 0.f};
#pragma unroll
        for (int q = 0; q < H2 / 64; ++q) {
          const int k = lane + q * 64;
          pr[0] += fast_tanh(sp[k] + hp1[k]) * aw[k];
          pr[1] += fast_tanh(sp[k] + hp2[k]) * aw[k];
        }
        wredsumN<2>(pr);
        if (lane == 0) {
          el[base] = __expf(pr[0]);
          if (v2) el[base + 4] = __expf(pr[1]);
        }
      }
      __syncthreads();
      if (wid == 0) {
        float p = (lane < TCH) ? el[lane] : 0.f;
        if (lane + 64 < TCH) p += el[lane + 64];
        p = wredsum1(p);
        if (lane == 0) cstore(&A.pden[b * NCH + ch], p);
      }
      float a0 = 0.f, a1 = 0.f, a2 = 0.f;
      const float* hb = A.hpack + (size_t)ch * TCH * H2;
#pragma unroll 5
      for (int ti = 0; ti < TCH; ++ti) {
        const float ev = el[ti];
        const float* hr = hb + (size_t)ti * H2;
        a0 += ev * hr[tid];
        a1 += ev * hr[tid + 256];
        if (tid < H2 - 512) a2 += ev * hr[tid + 512];
      }
      float* pgp = A.pg + (size_t)(b * NCH + ch) * H2;
      cstore(&pgp[tid], a0);
      cstore(&pgp[tid + 256], a1);
      if (tid < H2 - 512) cstore(&pgp[tid + 512], a2);
    }
    BAR();
    // ---- S3: reduce g, then pre = tanh(s@sy^T + g@gy^T + gy_b) ----
    {
      const int b = wg >> 4, r0 = (wg & 15) * 20;
      float* gl = sm;  // 640
      float den = 0.f;
#pragma unroll
      for (int c = 0; c < NCH; ++c) den += cload(&A.pden[b * NCH + c]);
      for (int k = tid; k < H2; k += DTH) {
        float s = 0.f;
#pragma unroll
        for (int c = 0; c < NCH; ++c) s += cload(&A.pg[(size_t)(b * NCH + c) * H2 + k]);
        s = s / den;
        gl[k] = s;
        if ((wg & 15) == 0) cstore(&A.gvec[b * H2 + k], s);
      }
      __syncthreads();
      float pr[5];
      const float* hb = hstL + b * H;
#pragma unroll
      for (int q = 0; q < 5; ++q) {
        const int j = r0 + wid * 5 + q;
        const float* syr = A.sy_w + (size_t)j * H;
        const float* gyr = A.gy_w + (size_t)j * H2;
        float p = 0.f;
#pragma unroll
        for (int mi = 0; mi < H / 64; ++mi) p += hb[lane + mi * 64] * syr[lane + mi * 64];
#pragma unroll
        for (int ki = 0; ki < H2 / 64; ++ki) p += gl[lane + ki * 64] * gyr[lane + ki * 64];
        pr[q] = p;
      }
      wredsumN<5>(pr);
      if (lane == 0) {
#pragma unroll
        for (int q = 0; q < 5; ++q) {
          const int j = r0 + wid * 5 + q;
          cstore(&A.pre[b * H + j], tanhf(pr[q] + A.gy_b[j]));
        }
      }
    }
    BAR();
    // ---- S5: gates-partial (WGs 0..15) || logits + top4 + expsum (WGs 16..63) ----
    if (wg < 16) {
      const int b = wg >> 2, j0 = (wg & 3) * 320;
      float* gb = sm;          // 640
      float* pb = sm + H2;     // 320
      const float* sb = hstL + b * H;
      for (int e = tid; e < H2; e += DTH) gb[e] = cload(&A.gvec[b * H2 + e]);
      for (int e = tid; e < H; e += DTH) pb[e] = cload(&A.pre[b * H + e]);
      __syncthreads();
      for (int g4 = 0; g4 < 20; ++g4) {
        float pr[4];
#pragma unroll
        for (int u = 0; u < 4; ++u) {
          const int j = j0 + wid * 80 + g4 * 4 + u;
          const float* ssr = A.ss_w + (size_t)j * H;
          const float* gsr = A.gs_w + (size_t)j * H2;
          const float* mr = A.Mm + (size_t)j * H;
          float p = 0.f;
#pragma unroll
          for (int mi = 0; mi < H / 64; ++mi) {
            const int m = lane + mi * 64;
            p += sb[m] * ssr[m] + pb[m] * mr[m];
          }
#pragma unroll
          for (int ki = 0; ki < H2 / 64; ++ki) {
            const int k = lane + ki * 64;
            p += gb[k] * gsr[k];
          }
          pr[u] = p;
        }
        wredsumN<4>(pr);
        if (lane == 0) {
#pragma unroll
          for (int u = 0; u < 4; ++u) {
            const int j = j0 + wid * 80 + g4 * 4 + u;
            cstore(&A.abuf[b * H4 + j], pr[u] + A.gs_b[j] + A.ys_b[j] + A.c1[j]);
          }
        }
      }
    } else {
      const int ch = wg - 16;
      const int v0 = ch * LROWS;
      const int cn_ = (V - v0 < LROWS) ? (V - v0) : LROWS;
      float* pl = sm;             // 1280: pre for 4 beams
      float* wsum = sm + 1536;    // [4 waves][4 beams]
      float* wtv = sm + 1552;     // [4][4][4]
      int* wti = (int*)(sm + 1616);
      for (int e = tid; e < BEAM * H; e += DTH) pl[e] = cload(&A.pre[e]);
      __syncthreads();
      float lg[4];
      const bool valid = tid < cn_;
      const int v = v0 + tid;
      if (valid) {
        const float* yr = A.yy_w + (size_t)v * H;
        float l0 = 0.f, l1 = 0.f, l2 = 0.f, l3 = 0.f;
#pragma unroll 4
        for (int m = 0; m < H; m += 4) {
          const float4 yv = *(const float4*)(yr + m);
          l0 += yv.x * pl[m] + yv.y * pl[m + 1] + yv.z * pl[m + 2] + yv.w * pl[m + 3];
          l1 += yv.x * pl[H + m] + yv.y * pl[H + m + 1] + yv.z * pl[H + m + 2] + yv.w * pl[H + m + 3];
          l2 += yv.x * pl[2 * H + m] + yv.y * pl[2 * H + m + 1] + yv.z * pl[2 * H + m + 2] + yv.w * pl[2 * H + m + 3];
          l3 += yv.x * pl[3 * H + m] + yv.y * pl[3 * H + m + 1] + yv.z * pl[3 * H + m + 2] + yv.w * pl[3 * H + m + 3];
        }
        const float bb = A.yy_b[v];
        lg[0] = l0 + bb; lg[1] = l1 + bb; lg[2] = l2 + bb; lg[3] = l3 + bb;
      } else {
        lg[0] = lg[1] = lg[2] = lg[3] = -3.402823466e38f;
      }
      {
        float es[4];
#pragma unroll
        for (int b = 0; b < 4; ++b) es[b] = valid ? __expf(lg[b]) : 0.f;
        wredsumN<4>(es);
        if (lane == 0) {
#pragma unroll
          for (int b = 0; b < 4; ++b) wsum[wid * 4 + b] = es[b];
        }
      }
      {
        float tv[4]; int tix[4];
#pragma unroll
        for (int b = 0; b < 4; ++b) { tv[b] = lg[b]; tix[b] = v; }
#pragma unroll
        for (int it = 0; it < 4; ++it) {
          float mv[4]; int mi_[4];
#pragma unroll
          for (int b = 0; b < 4; ++b) { mv[b] = tv[b]; mi_[b] = tix[b]; }
#pragma unroll
          for (int mm = 32; mm > 0; mm >>= 1) {
#pragma unroll
            for (int b = 0; b < 4; ++b) {
              const float ov = __shfl_xor(mv[b], mm, 64);
              const int oi = __shfl_xor(mi_[b], mm, 64);
              if (ov > mv[b] || (ov == mv[b] && oi < mi_[b])) { mv[b] = ov; mi_[b] = oi; }
            }
          }
          if (lane == 0) {
#pragma unroll
            for (int b = 0; b < 4; ++b) { wtv[(wid * 4 + b) * 4 + it] = mv[b]; wti[(wid * 4 + b) * 4 + it] = mi_[b]; }
          }
#pragma unroll
          for (int b = 0; b < 4; ++b)
            if (tix[b] == mi_[b]) tv[b] = -3.402823466e38f;
        }
      }
      __syncthreads();
      if (tid < BEAM) {
        const int b = tid;
        cstore(&A.pexp[ch * BEAM + b], (wsum[b] + wsum[4 + b]) + (wsum[8 + b] + wsum[12 + b]));
        float bv[4] = {-3.402823466e38f, -3.402823466e38f, -3.402823466e38f, -3.402823466e38f};
        int bi[4] = {0x7fffffff, 0x7fffffff, 0x7fffffff, 0x7fffffff};
        for (int wv = 0; wv < 4; ++wv)
          for (int q = 0; q < 4; ++q) insert4(bv, bi, wtv[(wv * 4 + b) * 4 + q], wti[(wv * 4 + b) * 4 + q]);
#pragma unroll
        for (int q = 0; q < 4; ++q) {
          cstore(&A.ptv[(ch * BEAM + b) * 4 + q], bv[q]);
          cstorei(&A.pti[(ch * BEAM + b) * 4 + q], bi[q]);
        }
      }
    }
    BAR();
    // ---- S6 (replicated in every WG): lse, global top-4, gates, cell, beam gather ----
    {
      float* pexps = sm;               // [4][48]
      float* stv = sm + 192;           // [768]
      int* sti = (int*)(sm + 960);     // [768]
      if (tid < LCH * BEAM) {
        const int b = tid & 3, w = tid >> 2;
        pexps[b * LCH + w] = cload(&A.pexp[w * BEAM + b]);
      }
      for (int e = tid; e < LCH * BEAM * 4; e += DTH) {
        stv[e] = cload(&A.ptv[e]);
        sti[e] = cloadi(&A.pti[e]);
      }
      __syncthreads();
      if (tid < BEAM) {
        float s_ = 0.f;
        for (int w = 0; w < LCH; ++w) s_ += pexps[tid * LCH + w];
        lse_sm[tid] = logf(s_);
      }
      __syncthreads();
      if (tid < BEAM) {
        const int b = tid;
        float bv[4] = {-3.402823466e38f, -3.402823466e38f, -3.402823466e38f, -3.402823466e38f};
        int bi[4] = {0x7fffffff, 0x7fffffff, 0x7fffffff, 0x7fffffff};
        for (int w = 0; w < LCH; ++w)
          for (int q = 0; q < 4; ++q) insert4(bv, bi, stv[(w * BEAM + b) * 4 + q], sti[(w * BEAM + b) * 4 + q]);
        const float sc = scl[b];
#pragma unroll
        for (int q = 0; q < 4; ++q) { cand_val[b * 4 + q] = sc + (bv[q] - lse_sm[b]); cand_tok[b * 4 + q] = bi[q]; }
      }
      __syncthreads();
      if (tid == 0) {
        float bv[4] = {-3.402823466e38f, -3.402823466e38f, -3.402823466e38f, -3.402823466e38f};
        int bf[4] = {0x7fffffff, 0x7fffffff, 0x7fffffff, 0x7fffffff};
        for (int f = 0; f < 16; ++f) insert4(bv, bf, cand_val[f], f);
#pragma unroll
        for (int q = 0; q < 4; ++q) {
          parent_s[q] = bf[q] >> 2;
          tok_s[q] = cand_tok[bf[q]];
          scl[q] = bv[q];
        }
      }
      __syncthreads();
      for (int e = tid; e < BEAM * H4; e += DTH) {
        const int b = e / H4, j = e - b * H4;
        sm[e] = tanhf(cload(&A.abuf[e]) - lse_sm[b] * A.c2[j]);
      }
      __syncthreads();
      float* cn2 = sm + 5120;
      float* hn2 = sm + 6400;
      for (int e = tid; e < BEAM * H; e += DTH) {
        const int b = e / H, jj = e - b * H;
        const float gi = sm[b * H4 + jj], gf = sm[b * H4 + H + jj];
        const float gc = sm[b * H4 + 2 * H + jj], go = sm[b * H4 + 3 * H + jj];
        const float ig = 0.5f * tanhf(0.5f * gi) + 0.5f;
        const float fg = 0.5f * tanhf(0.5f * gf) + 0.5f;
        const float og = 0.5f * tanhf(0.5f * go) + 0.5f;
        const float cv = fg * cstL[e] + ig * tanhf(gc);
        cn2[e] = cv;
        hn2[e] = og * tanhf(cv);
      }
      __syncthreads();
      for (int e = tid; e < BEAM * H; e += DTH) {
        const int b = e / H, jj = e - b * H;
        const int p = parent_s[b];
        cstL[e] = cn2[p * H + jj];
        hstL[e] = hn2[p * H + jj];
      }
      {
        int* src = seqL[step & 1];
        int* dst = seqL[(step & 1) ^ 1];
        for (int e = tid; e < BEAM * STEPS; e += DTH) {
          const int b = e / STEPS, ts = e - b * STEPS;
          dst[e] = (ts == step) ? tok_s[b] : src[parent_s[b] * STEPS + ts];
        }
      }
      __syncthreads();  // hstL/seq ready before next step's S1
    }
  }
  if (wg == 0) {
    for (int e = tid; e < BEAM * STEPS; e += DTH) A.out[e] = (float)seqL[0][e];
    if (tid < BEAM) A.out[BEAM * STEPS + tid] = scl[tid];
  }
}

}  // namespace

extern "C" void kernel_launch(void* const* d_in, const int* in_sizes, int n_in,
                              void* d_out, int out_size, void* d_ws, size_t ws_size,
                              hipStream_t stream) {
  (void)in_sizes; (void)n_in; (void)out_size; (void)ws_size;
  const float* data   = (const float*)d_in[0];
  const float* wih0   = (const float*)d_in[1];
  const float* whh0   = (const float*)d_in[2];
  const float* b0     = (const float*)d_in[3];
  const float* wihL   = (const float*)d_in[4];
  const float* whhL   = (const float*)d_in[5];
  const float* bL     = (const float*)d_in[6];
  const float* atts_w = (const float*)d_in[7];
  const float* atth_w = (const float*)d_in[8];
  const float* atth_b = (const float*)d_in[9];
  const float* attw_w = (const float*)d_in[10];
  const float* sy_w   = (const float*)d_in[11];
  const float* gy_w   = (const float*)d_in[12];
  const float* gy_b   = (const float*)d_in[13];
  const float* yy_w   = (const float*)d_in[14];
  const float* yy_b   = (const float*)d_in[15];
  const float* ss_w   = (const float*)d_in[16];
  const float* gs_w   = (const float*)d_in[17];
  const float* gs_b   = (const float*)d_in[18];
  const float* ys_w   = (const float*)d_in[19];
  const float* ys_b   = (const float*)d_in[20];

  float* W = (float*)d_ws;
  unsigned* cnt = (unsigned*)d_ws;
  (void)hipMemsetAsync(d_ws, 0, N_ZERO * sizeof(float), stream);

  // Mmat = ys_w @ yy_w, plus folded constants c1, c2
  {
    dim3 g(H / 64, H4 / 64, 1);
    gemm64<false><<<g, 256, 0, stream>>>(ys_w, yy_w, nullptr, W + O_MMAT, H4, H, V, 0, 0, 0);
  }
  c1c2k<<<H4, 256, 0, stream>>>(ys_w, yy_b, W + O_C1, W + O_C2);

  float* xp = W + O_XP;
  float* hA = W + O_HBA;
  float* hB = W + O_HBB;

  // ---- encoder ----
  {
    dim3 g(H4 / 64, (T_N + 63) / 64, 2);
    gemm64<true><<<g, 256, 0, stream>>>(data, wih0, b0, xp, T_N, H4, DIN,
                                        (size_t)H4 * DIN, H4, (size_t)T_N * H4);
  }
  lstm_scan<<<2 * EWG, ETH, 0, stream>>>(whh0, xp, hA, W + O_GBUF, cnt);
  for (int l = 1; l < NLAY; ++l) {
    const float* inb = (l & 1) ? hA : hB;
    float* outb = (l & 1) ? hB : hA;
    dim3 g(H4 / 64, (T_N + 63) / 64, 2);
    gemm64<true><<<g, 256, 0, stream>>>(inb, wihL + (size_t)(l - 1) * 2 * H4 * H2,
                                        bL + (size_t)(l - 1) * 2 * H4, xp, T_N, H4, H2,
                                        (size_t)H4 * H2, H4, (size_t)T_N * H4);
    lstm_scan<<<2 * EWG, ETH, 0, stream>>>(whhL + (size_t)(l - 1) * 2 * H4 * H, xp, outb,
                                           W + O_GBUF, cnt + l * 32);
  }
  const float* hfin = hB;  // layer 3 output

  // hproj = hpack @ atth_w^T + atth_b
  {
    dim3 g(H2 / 64, (T_N + 63) / 64, 1);
    gemm64<true><<<g, 256, 0, stream>>>(hfin, atth_w, atth_b, W + O_HPROJ, T_N, H2, H2, 0, 0, 0);
  }

  // ---- decoder ----
  DecArgs da;
  da.atts_w = atts_w; da.attw_w = attw_w;
  da.sy_w = sy_w; da.gy_w = gy_w; da.gy_b = gy_b;
  da.yy_w = yy_w; da.yy_b = yy_b;
  da.gs_b = gs_b; da.ys_b = ys_b;
  da.ss_w = ss_w; da.gs_w = gs_w;
  da.hpack = hfin; da.hproj = W + O_HPROJ; da.Mm = W + O_MMAT; da.c1 = W + O_C1; da.c2 = W + O_C2;
  da.sproj = W + O_SPROJ; da.pden = W + O_PDEN; da.pexp = W + O_PEXP; da.ptv = W + O_PTV;
  da.gvec = W + O_GVEC; da.pre = W + O_PRE; da.abuf = W + O_ABUF; da.pg = W + O_PG;
  da.pti = (int*)(W + O_PTI);
  da.cnt = cnt + 160;
  da.out = (float*)d_out;
  decoder<<<DWG, DTH, 0, stream>>>(da);
}

// Round 4
// 50768.948 us; speedup vs baseline: 1.7149x; 1.2357x over previous
//
#include <hip/hip_runtime.h>

#define DEVI __device__ __forceinline__

namespace {

constexpr int T_N   = 2000;
constexpr int DIN   = 120;
constexpr int H     = 320;
constexpr int H2    = 640;
constexpr int H4    = 1280;
constexpr int NLAY  = 4;
constexpr int V     = 10000;
constexpr int BEAM  = 4;
constexpr int STEPS = 200;

// ---- encoder scan config: 8 WGs/dir x 512 thr, 100 weights/thread in VGPRs ----
constexpr int SWG  = 8;
constexpr int STH  = 512;
constexpr int SROWS = H4 / SWG;       // 160 rows per WG
constexpr int SRW  = STH / 16;        // 32 row-workers (16 col-groups each)
constexpr int SRPT = SROWS / SRW;     // 5 rows per worker
constexpr int SKC  = H / 16;          // 20 cols per col-group

// ---- decoder config ----
constexpr int DWG = 64, DTH = 256;
constexpr int NCH = 64, TCH = 32;              // attention t-chunks
constexpr int LCH = 48;                        // logits chunks
constexpr int LROWS = (V + LCH - 1) / LCH;     // 209
constexpr int GWG = 16, GROWS = H4 / GWG;      // 80 gate rows per WG

// ---- workspace layout (float offsets) ----
constexpr size_t N_ZERO   = 2048;                      // flags region (ints), zeroed
constexpr size_t O_SPROJ  = 2048;                      // [4][640]
constexpr size_t O_PDEN   = O_SPROJ + BEAM * H2;       // [4][64]
constexpr size_t O_PEXP   = O_PDEN + BEAM * NCH;       // [48][4]
constexpr size_t O_PTV    = O_PEXP + LCH * BEAM;       // [48][4][4]
constexpr size_t O_PTI    = O_PTV + LCH * BEAM * 4;    // int [48][4][4]
constexpr size_t O_GVEC   = O_PTI + LCH * BEAM * 4;    // [4][640]
constexpr size_t O_PRE    = O_GVEC + BEAM * H2;        // [4][320]
constexpr size_t O_ABUF   = O_PRE + BEAM * H;          // [4][1280]
constexpr size_t O_PG     = O_ABUF + BEAM * H4;        // [64][4][640]
constexpr size_t O_GBUF   = O_PG + (size_t)NCH * BEAM * H2;  // [2 dir][2 pp][1280]
constexpr size_t O_C1     = O_GBUF + 4 * H4;
constexpr size_t O_C2     = O_C1 + H4;
constexpr size_t O_MMAT   = O_C2 + H4;                 // [1280][320]
constexpr size_t O_HPROJ  = O_MMAT + (size_t)H4 * H;   // [2000][640]
constexpr size_t O_HBA    = O_HPROJ + (size_t)T_N * H2;
constexpr size_t O_HBB    = O_HBA + (size_t)T_N * H2;
constexpr size_t O_XP     = O_HBB + (size_t)T_N * H2;  // [2][2000][1280]

// ---- coherent (cache-bypassing) accessors for cross-WG data ----
DEVI float cload(const float* p) {
  return __hip_atomic_load((float*)p, __ATOMIC_RELAXED, __HIP_MEMORY_SCOPE_SYSTEM);
}
DEVI int cloadi(const int* p) {
  return __hip_atomic_load((int*)p, __ATOMIC_RELAXED, __HIP_MEMORY_SCOPE_SYSTEM);
}
DEVI unsigned cloadu(const unsigned* p) {
  return __hip_atomic_load((unsigned*)p, __ATOMIC_RELAXED, __HIP_MEMORY_SCOPE_SYSTEM);
}
DEVI void cstore(float* p, float v) {
  __hip_atomic_store(p, v, __ATOMIC_RELAXED, __HIP_MEMORY_SCOPE_SYSTEM);
}
DEVI void cstorei(int* p, int v) {
  __hip_atomic_store(p, v, __ATOMIC_RELAXED, __HIP_MEMORY_SCOPE_SYSTEM);
}
DEVI void cstoreu(unsigned* p, unsigned v) {
  __hip_atomic_store(p, v, __ATOMIC_RELAXED, __HIP_MEMORY_SCOPE_SYSTEM);
}

DEVI float wredsum1(float v) {
#pragma unroll
  for (int m = 32; m > 0; m >>= 1) v += __shfl_xor(v, m, 64);
  return v;
}

template <int N>
DEVI void wredsumN(float* a) {
#pragma unroll
  for (int m = 32; m > 0; m >>= 1) {
#pragma unroll
    for (int i = 0; i < N; ++i) a[i] += __shfl_xor(a[i], m, 64);
  }
}

DEVI float sg(float x) { return 0.5f * tanhf(0.5f * x) + 0.5f; }  // sigmoid (jax form)

DEVI float fast_tanh(float x) {  // overflow-safe; used in attention feed-forward
  float ax = fabsf(x);
  float z = __expf(-2.f * ax);
  float t = 1.f - 2.f * z / (1.f + z);
  return x < 0.f ? -t : t;
}

DEVI void insert4(float* bv, int* bi, float v, int ix) {
#pragma unroll
  for (int s = 0; s < 4; ++s) {
    if (v > bv[s] || (v == bv[s] && ix < bi[s])) {
      float tv = bv[s]; int ti = bi[s];
      bv[s] = v; bi[s] = ix; v = tv; ix = ti;
    }
  }
}

// ======================= tiled fp32 GEMM =======================
template <bool BT>
__global__ __launch_bounds__(256) void gemm64(
    const float* __restrict__ A, const float* __restrict__ B,
    const float* __restrict__ bias, float* __restrict__ C,
    int M, int N, int K, size_t sB, size_t sBias, size_t sC) {
  __shared__ float As[16][68];
  __shared__ float Bs[16][68];
  const int tid = threadIdx.x;
  const int tx = tid & 15, ty = tid >> 4;
  const int n0 = blockIdx.x * 64, m0 = blockIdx.y * 64;
  const float* Bz = B + (size_t)blockIdx.z * sB;
  float acc[4][4] = {};
  for (int kk = 0; kk < K; kk += 16) {
    {
      const int m = tid >> 2, kq = (tid & 3) << 2;
      float4 v = make_float4(0.f, 0.f, 0.f, 0.f);
      if (m0 + m < M) {
        if (kk + kq + 3 < K) {
          v = *(const float4*)(A + (size_t)(m0 + m) * K + kk + kq);
        } else {
          float t0 = (kk + kq + 0 < K) ? A[(size_t)(m0 + m) * K + kk + kq + 0] : 0.f;
          float t1 = (kk + kq + 1 < K) ? A[(size_t)(m0 + m) * K + kk + kq + 1] : 0.f;
          float t2 = (kk + kq + 2 < K) ? A[(size_t)(m0 + m) * K + kk + kq + 2] : 0.f;
          float t3 = (kk + kq + 3 < K) ? A[(size_t)(m0 + m) * K + kk + kq + 3] : 0.f;
          v = make_float4(t0, t1, t2, t3);
        }
      }
      As[kq + 0][m] = v.x; As[kq + 1][m] = v.y; As[kq + 2][m] = v.z; As[kq + 3][m] = v.w;
    }
    if (BT) {
      const int n = tid >> 2, kq = (tid & 3) << 2;
      float4 v = make_float4(0.f, 0.f, 0.f, 0.f);
      if (kk + kq + 3 < K) {
        v = *(const float4*)(Bz + (size_t)(n0 + n) * K + kk + kq);
      } else {
        float t0 = (kk + kq + 0 < K) ? Bz[(size_t)(n0 + n) * K + kk + kq + 0] : 0.f;
        float t1 = (kk + kq + 1 < K) ? Bz[(size_t)(n0 + n) * K + kk + kq + 1] : 0.f;
        float t2 = (kk + kq + 2 < K) ? Bz[(size_t)(n0 + n) * K + kk + kq + 2] : 0.f;
        float t3 = (kk + kq + 3 < K) ? Bz[(size_t)(n0 + n) * K + kk + kq + 3] : 0.f;
        v = make_float4(t0, t1, t2, t3);
      }
      Bs[kq + 0][n] = v.x; Bs[kq + 1][n] = v.y; Bs[kq + 2][n] = v.z; Bs[kq + 3][n] = v.w;
    } else {
      const int kr = tid >> 4, nq = (tid & 15) << 2;
      float4 v = make_float4(0.f, 0.f, 0.f, 0.f);
      if (kk + kr < K) v = *(const float4*)(Bz + (size_t)(kk + kr) * N + n0 + nq);
      *(float4*)&Bs[kr][nq] = v;
    }
    __syncthreads();
#pragma unroll
    for (int k = 0; k < 16; ++k) {
      const float4 a = *(const float4*)&As[k][ty << 2];
      const float4 b = *(const float4*)&Bs[k][tx << 2];
      acc[0][0] += a.x * b.x; acc[0][1] += a.x * b.y; acc[0][2] += a.x * b.z; acc[0][3] += a.x * b.w;
      acc[1][0] += a.y * b.x; acc[1][1] += a.y * b.y; acc[1][2] += a.y * b.z; acc[1][3] += a.y * b.w;
      acc[2][0] += a.z * b.x; acc[2][1] += a.z * b.y; acc[2][2] += a.z * b.z; acc[2][3] += a.z * b.w;
      acc[3][0] += a.w * b.x; acc[3][1] += a.w * b.y; acc[3][2] += a.w * b.z; acc[3][3] += a.w * b.w;
    }
    __syncthreads();
  }
#pragma unroll
  for (int i = 0; i < 4; ++i) {
    const int m = m0 + (ty << 2) + i;
    if (m < M) {
#pragma unroll
      for (int j = 0; j < 4; ++j) {
        const int n = n0 + (tx << 2) + j;
        float v = acc[i][j];
        if (bias) v += bias[blockIdx.z * sBias + n];
        C[(size_t)blockIdx.z * sC + (size_t)m * N + n] = v;
      }
    }
  }
}

// c1[j] = sum_v ys_w[j,v]*yy_b[v] ; c2[j] = sum_v ys_w[j,v]
__global__ __launch_bounds__(256) void c1c2k(
    const float* __restrict__ ys_w, const float* __restrict__ yy_b,
    float* __restrict__ c1, float* __restrict__ c2) {
  const int j = blockIdx.x;
  const float* row = ys_w + (size_t)j * V;
  float s1 = 0.f, s2 = 0.f;
  for (int v = threadIdx.x; v < V; v += 256) {
    const float w = row[v];
    s1 += w * yy_b[v];
    s2 += w;
  }
  s1 = wredsum1(s1); s2 = wredsum1(s2);
  __shared__ float r1[4], r2[4];
  if ((threadIdx.x & 63) == 0) { r1[threadIdx.x >> 6] = s1; r2[threadIdx.x >> 6] = s2; }
  __syncthreads();
  if (threadIdx.x == 0) {
    c1[j] = (r1[0] + r1[1]) + (r1[2] + r1[3]);
    c2[j] = (r2[0] + r2[1]) + (r2[2] + r2[3]);
  }
}

// ======================= BiLSTM recurrent scan =======================
// 16 WGs (8/dir x 512 thr). 100 whh weights/thread in VGPRs; 16-lane shuffle
// reduce; flag-store arrival + 8-flag wave-poll (no RMW serialization);
// xp software-prefetched under the poll window.
__global__ __launch_bounds__(STH, 1) void lstm_scan(
    const float* __restrict__ whh,    // [2][H4][H]
    const float* __restrict__ xproj,  // [2][T][H4]
    float* __restrict__ hpack,        // [T][H2]
    float* __restrict__ gbuf,         // [2 dir][2 pp][1280]
    unsigned* __restrict__ flags)     // [2 dir][SWG] stride-16 ints
{
  const int wg = blockIdx.x;
  const int dir = wg / SWG, wl = wg - dir * SWG;
  const int tid = threadIdx.x;
  const int lane = tid & 63, wid = tid >> 6;
  const int cg = tid & 15, rw = tid >> 4;
  const int rbase = wl * SROWS + rw * SRPT;
  const float* Wd = whh + (size_t)dir * H4 * H;
  const float* xp = xproj + (size_t)dir * T_N * H4;
  unsigned* fl = flags + (size_t)dir * SWG * 16;

  float w[SRPT][SKC];
#pragma unroll
  for (int i = 0; i < SRPT; ++i) {
    const float* wr = Wd + (size_t)(rbase + i) * H + cg * SKC;
#pragma unroll
    for (int j = 0; j < SKC; ++j) w[i][j] = wr[j];
  }

  __shared__ float hlds[H];
  for (int e = tid; e < H; e += STH) hlds[e] = 0.f;
  float creg = 0.f;
  float xv[SRPT];
  if (cg == 0) {
    const int tt0 = dir ? (T_N - 1) : 0;
#pragma unroll
    for (int i = 0; i < SRPT; ++i) xv[i] = xp[(size_t)tt0 * H4 + rbase + i];
  }
  __syncthreads();

  for (int t = 0; t < T_N; ++t) {
    const int tt = dir ? (T_N - 1 - t) : t;
    float acc[SRPT] = {};
#pragma unroll
    for (int j4 = 0; j4 < SKC / 4; ++j4) {
      const float4 hv = *(const float4*)&hlds[cg * SKC + j4 * 4];
#pragma unroll
      for (int i = 0; i < SRPT; ++i)
        acc[i] += w[i][j4 * 4 + 0] * hv.x + w[i][j4 * 4 + 1] * hv.y +
                  w[i][j4 * 4 + 2] * hv.z + w[i][j4 * 4 + 3] * hv.w;
    }
#pragma unroll
    for (int m = 1; m <= 8; m <<= 1) {
#pragma unroll
      for (int i = 0; i < SRPT; ++i) acc[i] += __shfl_xor(acc[i], m, 64);
    }
    float* gslot = gbuf + (size_t)(dir * 2 + (t & 1)) * H4;
    if (cg == 0) {
#pragma unroll
      for (int i = 0; i < SRPT; ++i) cstore(&gslot[rbase + i], acc[i] + xv[i]);
    }
    __syncthreads();  // drains vmcnt per wave: gslot stores ack'd at coherence point
    if (tid == 0) cstoreu(&fl[wl * 16], (unsigned)(t + 1));
    if (cg == 0 && t + 1 < T_N) {  // prefetch next xp under the poll window
      const int tn2 = dir ? (T_N - 2 - t) : (t + 1);
#pragma unroll
      for (int i = 0; i < SRPT; ++i) xv[i] = xp[(size_t)tn2 * H4 + rbase + i];
    }
    if (wid == 0) {
      const unsigned tgt = (unsigned)(t + 1);
      for (;;) {
        const unsigned f = (lane < SWG) ? cloadu(&fl[lane * 16]) : 0xFFFFFFFFu;
        if (__all(f >= tgt)) break;
        __builtin_amdgcn_s_sleep(2);
      }
    }
    __syncthreads();
    // gate nonlinearity + state update (replicated per WG of the direction)
    if (tid < H) {
      const float gi = cload(&gslot[tid]);
      const float gf = cload(&gslot[tid + H]);
      const float gc = cload(&gslot[tid + 2 * H]);
      const float go = cload(&gslot[tid + 3 * H]);
      creg = sg(gf) * creg + sg(gi) * tanhf(gc);
      const float h = sg(go) * tanhf(creg);
      hlds[tid] = h;
      if (wl == 0) hpack[(size_t)tt * H2 + dir * H + tid] = h;
    }
    __syncthreads();
  }
}

// ======================= persistent beam-search decoder =======================
struct DecArgs {
  const float* atts_w; const float* attw_w;
  const float* sy_w; const float* gy_w; const float* gy_b;
  const float* yy_w; const float* yy_b;
  const float* gs_b; const float* ys_b;
  const float* ss_w; const float* gs_w;
  const float* hpack; const float* hproj; const float* Mm; const float* c1; const float* c2;
  float* sproj; float* pden; float* pexp; float* ptv;
  float* gvec; float* pre; float* abuf; float* pg;
  int* pti;
  unsigned* flags;
  float* out;
};

__global__ __launch_bounds__(DTH, 1) void decoder(DecArgs A) {
  const int wg = blockIdx.x, tid = threadIdx.x;
  const int wid = tid >> 6, lane = tid & 63;
  __shared__ float sm[8192];
  __shared__ float cstL[BEAM * H];   // beam cell state (replicated per WG)
  __shared__ float hstL[BEAM * H];   // beam hidden state
  __shared__ int   seqL[2][BEAM * STEPS];
  __shared__ float scl[BEAM];
  __shared__ float lse_sm[BEAM];
  __shared__ float cand_val[16];
  __shared__ int cand_tok[16];
  __shared__ int parent_s[BEAM];
  __shared__ int tok_s[BEAM];
  unsigned barEra = 0;

  // flag barrier: arrival = store own slot; poll = wave0 reads all 64 flags
  auto BAR = [&]() {
    barEra += 1;
    __syncthreads();  // all prior stores drained (vmcnt(0) per wave before s_barrier)
    if (tid == 0) cstoreu(&A.flags[wg * 16], barEra);
    if (wid == 0) {
      for (;;) {
        const unsigned f = cloadu(&A.flags[lane * 16]);
        if (__all(f >= barEra)) break;
        __builtin_amdgcn_s_sleep(4);
      }
    }
    __syncthreads();
  };

  // sproj[b] = hstL[b] @ atts_w^T  (one beam per WG, wg<4)
  auto do_sproj = [&](int b) {
    const int kk = wid * 160 + lane;
    float a0 = 0.f, a1 = 0.f, a2 = 0.f;
    const float* w0 = A.atts_w + (size_t)kk * H;
    const float* w1 = A.atts_w + (size_t)(kk + 64) * H;
    const float* w2 = A.atts_w + (size_t)(kk + 128) * H;
    for (int m4 = 0; m4 < H / 4; ++m4) {
      const float4 sv = *(const float4*)&hstL[b * H + m4 * 4];
      const float4 v0 = *(const float4*)(w0 + m4 * 4);
      a0 += v0.x * sv.x + v0.y * sv.y + v0.z * sv.z + v0.w * sv.w;
      const float4 v1 = *(const float4*)(w1 + m4 * 4);
      a1 += v1.x * sv.x + v1.y * sv.y + v1.z * sv.z + v1.w * sv.w;
      if (lane < 32) {
        const float4 v2 = *(const float4*)(w2 + m4 * 4);
        a2 += v2.x * sv.x + v2.y * sv.y + v2.z * sv.z + v2.w * sv.w;
      }
    }
    cstore(&A.sproj[b * H2 + kk], a0);
    cstore(&A.sproj[b * H2 + kk + 64], a1);
    if (lane < 32) cstore(&A.sproj[b * H2 + kk + 128], a2);
  };

  for (int e = tid; e < BEAM * H; e += DTH) { cstL[e] = 0.f; hstL[e] = 0.f; }
  if (tid < BEAM) scl[tid] = (tid == 0) ? 0.f : -1e9f;
  __syncthreads();
  if (wg < 4) do_sproj(wg);
  BAR();

  for (int step = 0; step < STEPS; ++step) {
    // ---- P1: attention (all beams per WG; chunk = wg) ----
    {
      const int ch = wg;
      const int t0 = ch * TCH;
      const int tn0 = T_N - t0;
      const int tn = tn0 < 0 ? 0 : (tn0 > TCH ? TCH : tn0);
      float* el = sm;             // [4][32]
      float* spl = sm + 128;      // [4][640] staged sproj
      for (int e = tid; e < BEAM * H2; e += DTH) spl[e] = cload(&A.sproj[e]);
      __syncthreads();
      float spr[4][10], awr[10];
#pragma unroll
      for (int q = 0; q < 10; ++q) awr[q] = A.attw_w[lane + q * 64];
#pragma unroll
      for (int b = 0; b < 4; ++b)
#pragma unroll
        for (int q = 0; q < 10; ++q) spr[b][q] = spl[b * H2 + lane + q * 64];
      for (int tl = wid; tl < tn; tl += 4) {
        const float* hp = A.hproj + (size_t)(t0 + tl) * H2;
        float hpr[10];
#pragma unroll
        for (int q = 0; q < 10; ++q) hpr[q] = hp[lane + q * 64];
        float dt[4] = {0.f, 0.f, 0.f, 0.f};
#pragma unroll
        for (int q = 0; q < 10; ++q) {
#pragma unroll
          for (int b = 0; b < 4; ++b) dt[b] += fast_tanh(spr[b][q] + hpr[q]) * awr[q];
        }
        wredsumN<4>(dt);
        if (lane == 0) {
#pragma unroll
          for (int b = 0; b < 4; ++b) el[b * TCH + tl] = __expf(dt[b]);
        }
      }
      __syncthreads();
      if (wid == 0) {
        float p[4];
#pragma unroll
        for (int b = 0; b < 4; ++b) p[b] = (lane < tn) ? el[b * TCH + lane] : 0.f;
        wredsumN<4>(p);
        if (lane == 0) {
#pragma unroll
          for (int b = 0; b < 4; ++b) cstore(&A.pden[b * NCH + ch], p[b]);
        }
      }
      float a0[4] = {}, a1[4] = {}, a2[4] = {};
      for (int tl = 0; tl < tn; ++tl) {
        const float* hr = A.hpack + (size_t)(t0 + tl) * H2;
        const float e0 = el[0 * TCH + tl], e1 = el[1 * TCH + tl];
        const float e2 = el[2 * TCH + tl], e3 = el[3 * TCH + tl];
        const float h0 = hr[tid], h1 = hr[tid + 256];
        const float h2 = (tid < H2 - 512) ? hr[tid + 512] : 0.f;
        a0[0] += e0 * h0; a0[1] += e1 * h0; a0[2] += e2 * h0; a0[3] += e3 * h0;
        a1[0] += e0 * h1; a1[1] += e1 * h1; a1[2] += e2 * h1; a1[3] += e3 * h1;
        a2[0] += e0 * h2; a2[1] += e1 * h2; a2[2] += e2 * h2; a2[3] += e3 * h2;
      }
      float* pgc = A.pg + (size_t)ch * BEAM * H2;
#pragma unroll
      for (int b = 0; b < 4; ++b) {
        cstore(&pgc[b * H2 + tid], a0[b]);
        cstore(&pgc[b * H2 + tid + 256], a1[b]);
        if (tid < H2 - 512) cstore(&pgc[b * H2 + tid + 512], a2[b]);
      }
    }
    BAR();
    // ---- P2: g-reduce over 64 chunks; 40 (b,k) per WG ----
    {
      float* smden = sm;  // [4]
      if (tid >= 40 && tid < 44) {
        const int b = tid - 40;
        float s = 0.f;
        for (int c = 0; c < NCH; ++c) s += cload(&A.pden[b * NCH + c]);
        smden[b] = s;
      }
      float s = 0.f;
      const int idx = wg * 40 + tid;
      if (tid < 40) {
        for (int c = 0; c < NCH; ++c) s += cload(&A.pg[(size_t)c * BEAM * H2 + idx]);
      }
      __syncthreads();
      if (tid < 40) {
        const int b = idx / H2;
        cstore(&A.gvec[idx], s / smden[b]);
      }
    }
    BAR();
    // ---- P3: pre = tanh(s@sy^T + g@gy^T + gy_b); 5 rows/WG, wave-per-beam ----
    {
      const int b = wid;
      const int j0 = wg * 5;
      float svr[5], gvr[10];
#pragma unroll
      for (int mi = 0; mi < 5; ++mi) svr[mi] = hstL[b * H + lane + mi * 64];
#pragma unroll
      for (int q = 0; q < 10; ++q) gvr[q] = cload(&A.gvec[b * H2 + lane + q * 64]);
      float pr[5];
#pragma unroll
      for (int r = 0; r < 5; ++r) {
        const int j = j0 + r;
        const float* syr = A.sy_w + (size_t)j * H;
        const float* gyr = A.gy_w + (size_t)j * H2;
        float p = 0.f;
#pragma unroll
        for (int mi = 0; mi < 5; ++mi) p += svr[mi] * syr[lane + mi * 64];
#pragma unroll
        for (int q = 0; q < 10; ++q) p += gvr[q] * gyr[lane + q * 64];
        pr[r] = p;
      }
      wredsumN<5>(pr);
      if (lane == 0) {
#pragma unroll
        for (int r = 0; r < 5; ++r)
          cstore(&A.pre[b * H + j0 + r], tanhf(pr[r] + A.gy_b[j0 + r]));
      }
    }
    BAR();
    // ---- P4: gates (WGs 0..15, all beams) || logits+top4+expsum (WGs 16..63) ----
    if (wg < GWG) {
      float* sgv = sm;            // [4][640]
      float* spv = sm + 2560;     // [4][320]
      for (int e = tid; e < BEAM * H2; e += DTH) sgv[e] = cload(&A.gvec[e]);
      for (int e = tid; e < BEAM * H; e += DTH) spv[e] = cload(&A.pre[e]);
      __syncthreads();
      float svv[4][5], pvv[4][5], gvv[4][10];
#pragma unroll
      for (int b = 0; b < 4; ++b) {
#pragma unroll
        for (int mi = 0; mi < 5; ++mi) {
          svv[b][mi] = hstL[b * H + lane + mi * 64];
          pvv[b][mi] = spv[b * H + lane + mi * 64];
        }
#pragma unroll
        for (int q = 0; q < 10; ++q) gvv[b][q] = sgv[b * H2 + lane + q * 64];
      }
      const int jb = wg * GROWS + wid * 20;
      for (int r = 0; r < 20; ++r) {
        const int j = jb + r;
        const float* ssr = A.ss_w + (size_t)j * H;
        const float* mr = A.Mm + (size_t)j * H;
        const float* gsr = A.gs_w + (size_t)j * H2;
        float pr[4] = {0.f, 0.f, 0.f, 0.f};
#pragma unroll
        for (int mi = 0; mi < 5; ++mi) {
          const float ssv = ssr[lane + mi * 64];
          const float mv = mr[lane + mi * 64];
#pragma unroll
          for (int b = 0; b < 4; ++b) pr[b] += svv[b][mi] * ssv + pvv[b][mi] * mv;
        }
#pragma unroll
        for (int q = 0; q < 10; ++q) {
          const float gsv = gsr[lane + q * 64];
#pragma unroll
          for (int b = 0; b < 4; ++b) pr[b] += gvv[b][q] * gsv;
        }
        wredsumN<4>(pr);
        if (lane == 0) {
          const float cb = A.gs_b[j] + A.ys_b[j] + A.c1[j];
#pragma unroll
          for (int b = 0; b < 4; ++b) cstore(&A.abuf[b * H4 + j], pr[b] + cb);
        }
      }
    } else {
      const int ch = wg - GWG;
      const int v0 = ch * LROWS;
      const int cn_ = (V - v0 < LROWS) ? (V - v0) : LROWS;
      float* pl = sm;             // 1280: pre for 4 beams
      float* wsum = sm + 1536;    // [4 waves][4 beams]
      float* wtv = sm + 1552;     // [4][4][4]
      int* wti = (int*)(sm + 1616);
      for (int e = tid; e < BEAM * H; e += DTH) pl[e] = cload(&A.pre[e]);
      __syncthreads();
      float lg[4];
      const bool valid = tid < cn_;
      const int v = v0 + tid;
      if (valid) {
        const float* yr = A.yy_w + (size_t)v * H;
        float l0 = 0.f, l1 = 0.f, l2 = 0.f, l3 = 0.f;
#pragma unroll 4
        for (int m = 0; m < H; m += 4) {
          const float4 yv = *(const float4*)(yr + m);
          l0 += yv.x * pl[m] + yv.y * pl[m + 1] + yv.z * pl[m + 2] + yv.w * pl[m + 3];
          l1 += yv.x * pl[H + m] + yv.y * pl[H + m + 1] + yv.z * pl[H + m + 2] + yv.w * pl[H + m + 3];
          l2 += yv.x * pl[2 * H + m] + yv.y * pl[2 * H + m + 1] + yv.z * pl[2 * H + m + 2] + yv.w * pl[2 * H + m + 3];
          l3 += yv.x * pl[3 * H + m] + yv.y * pl[3 * H + m + 1] + yv.z * pl[3 * H + m + 2] + yv.w * pl[3 * H + m + 3];
        }
        const float bb = A.yy_b[v];
        lg[0] = l0 + bb; lg[1] = l1 + bb; lg[2] = l2 + bb; lg[3] = l3 + bb;
      } else {
        lg[0] = lg[1] = lg[2] = lg[3] = -3.402823466e38f;
      }
      {
        float es[4];
#pragma unroll
        for (int b = 0; b < 4; ++b) es[b] = valid ? __expf(lg[b]) : 0.f;
        wredsumN<4>(es);
        if (lane == 0) {
#pragma unroll
          for (int b = 0; b < 4; ++b) wsum[wid * 4 + b] = es[b];
        }
      }
      {
        float tv[4]; int tix[4];
#pragma unroll
        for (int b = 0; b < 4; ++b) { tv[b] = lg[b]; tix[b] = v; }
#pragma unroll
        for (int it = 0; it < 4; ++it) {
          float mv[4]; int mi_[4];
#pragma unroll
          for (int b = 0; b < 4; ++b) { mv[b] = tv[b]; mi_[b] = tix[b]; }
#pragma unroll
          for (int mm = 32; mm > 0; mm >>= 1) {
#pragma unroll
            for (int b = 0; b < 4; ++b) {
              const float ov = __shfl_xor(mv[b], mm, 64);
              const int oi = __shfl_xor(mi_[b], mm, 64);
              if (ov > mv[b] || (ov == mv[b] && oi < mi_[b])) { mv[b] = ov; mi_[b] = oi; }
            }
          }
          if (lane == 0) {
#pragma unroll
            for (int b = 0; b < 4; ++b) { wtv[(wid * 4 + b) * 4 + it] = mv[b]; wti[(wid * 4 + b) * 4 + it] = mi_[b]; }
          }
#pragma unroll
          for (int b = 0; b < 4; ++b)
            if (tix[b] == mi_[b]) tv[b] = -3.402823466e38f;
        }
      }
      __syncthreads();
      if (tid < BEAM) {
        const int b = tid;
        cstore(&A.pexp[ch * BEAM + b], (wsum[b] + wsum[4 + b]) + (wsum[8 + b] + wsum[12 + b]));
        float bv[4] = {-3.402823466e38f, -3.402823466e38f, -3.402823466e38f, -3.402823466e38f};
        int bi[4] = {0x7fffffff, 0x7fffffff, 0x7fffffff, 0x7fffffff};
        for (int wv = 0; wv < 4; ++wv)
          for (int q = 0; q < 4; ++q) insert4(bv, bi, wtv[(wv * 4 + b) * 4 + q], wti[(wv * 4 + b) * 4 + q]);
#pragma unroll
        for (int q = 0; q < 4; ++q) {
          cstore(&A.ptv[(ch * BEAM + b) * 4 + q], bv[q]);
          cstorei(&A.pti[(ch * BEAM + b) * 4 + q], bi[q]);
        }
      }
    }
    BAR();
    // ---- P5 (replicated): lse, global top-4, gates, cell, beam gather + sproj ----
    {
      float* pexps = sm;               // [4][48]
      float* stv = sm + 192;           // [768]
      int* sti = (int*)(sm + 960);     // [768]
      if (tid < LCH * BEAM) {
        const int b = tid & 3, w = tid >> 2;
        pexps[b * LCH + w] = cload(&A.pexp[w * BEAM + b]);
      }
      for (int e = tid; e < LCH * BEAM * 4; e += DTH) {
        stv[e] = cload(&A.ptv[e]);
        sti[e] = cloadi(&A.pti[e]);
      }
      __syncthreads();
      if (tid < BEAM) {
        float s_ = 0.f;
        for (int w = 0; w < LCH; ++w) s_ += pexps[tid * LCH + w];
        lse_sm[tid] = logf(s_);
      }
      __syncthreads();
      if (tid < BEAM) {
        const int b = tid;
        float bv[4] = {-3.402823466e38f, -3.402823466e38f, -3.402823466e38f, -3.402823466e38f};
        int bi[4] = {0x7fffffff, 0x7fffffff, 0x7fffffff, 0x7fffffff};
        for (int w = 0; w < LCH; ++w)
          for (int q = 0; q < 4; ++q) insert4(bv, bi, stv[(w * BEAM + b) * 4 + q], sti[(w * BEAM + b) * 4 + q]);
        const float sc = scl[b];
#pragma unroll
        for (int q = 0; q < 4; ++q) { cand_val[b * 4 + q] = sc + (bv[q] - lse_sm[b]); cand_tok[b * 4 + q] = bi[q]; }
      }
      __syncthreads();
      if (tid == 0) {
        float bv[4] = {-3.402823466e38f, -3.402823466e38f, -3.402823466e38f, -3.402823466e38f};
        int bf[4] = {0x7fffffff, 0x7fffffff, 0x7fffffff, 0x7fffffff};
        for (int f = 0; f < 16; ++f) insert4(bv, bf, cand_val[f], f);
#pragma unroll
        for (int q = 0; q < 4; ++q) {
          parent_s[q] = bf[q] >> 2;
          tok_s[q] = cand_tok[bf[q]];
          scl[q] = bv[q];
        }
      }
      __syncthreads();
      for (int e = tid; e < BEAM * H4; e += DTH) {
        const int b = e / H4, j = e - b * H4;
        sm[e] = tanhf(cload(&A.abuf[e]) - lse_sm[b] * A.c2[j]);
      }
      __syncthreads();
      float* cn2 = sm + 5120;
      float* hn2 = sm + 6400;
      for (int e = tid; e < BEAM * H; e += DTH) {
        const int b = e / H, jj = e - b * H;
        const float gi = sm[b * H4 + jj], gf = sm[b * H4 + H + jj];
        const float gc = sm[b * H4 + 2 * H + jj], go = sm[b * H4 + 3 * H + jj];
        const float ig = 0.5f * tanhf(0.5f * gi) + 0.5f;
        const float fg = 0.5f * tanhf(0.5f * gf) + 0.5f;
        const float og = 0.5f * tanhf(0.5f * go) + 0.5f;
        const float cv = fg * cstL[e] + ig * tanhf(gc);
        cn2[e] = cv;
        hn2[e] = og * tanhf(cv);
      }
      __syncthreads();
      for (int e = tid; e < BEAM * H; e += DTH) {
        const int b = e / H, jj = e - b * H;
        const int p = parent_s[b];
        cstL[e] = cn2[p * H + jj];
        hstL[e] = hn2[p * H + jj];
      }
      {
        int* src = seqL[step & 1];
        int* dst = seqL[(step & 1) ^ 1];
        for (int e = tid; e < BEAM * STEPS; e += DTH) {
          const int b = e / STEPS, ts = e - b * STEPS;
          dst[e] = (ts == step) ? tok_s[b] : src[parent_s[b] * STEPS + ts];
        }
      }
      __syncthreads();  // hstL ready
      if (wg < 4) do_sproj(wg);
    }
    BAR();
  }
  if (wg == 0) {
    for (int e = tid; e < BEAM * STEPS; e += DTH) A.out[e] = (float)seqL[0][e];
    if (tid < BEAM) A.out[BEAM * STEPS + tid] = scl[tid];
  }
}

}  // namespace

extern "C" void kernel_launch(void* const* d_in, const int* in_sizes, int n_in,
                              void* d_out, int out_size, void* d_ws, size_t ws_size,
                              hipStream_t stream) {
  (void)in_sizes; (void)n_in; (void)out_size; (void)ws_size;
  const float* data   = (const float*)d_in[0];
  const float* wih0   = (const float*)d_in[1];
  const float* whh0   = (const float*)d_in[2];
  const float* b0     = (const float*)d_in[3];
  const float* wihL   = (const float*)d_in[4];
  const float* whhL   = (const float*)d_in[5];
  const float* bL     = (const float*)d_in[6];
  const float* atts_w = (const float*)d_in[7];
  const float* atth_w = (const float*)d_in[8];
  const float* atth_b = (const float*)d_in[9];
  const float* attw_w = (const float*)d_in[10];
  const float* sy_w   = (const float*)d_in[11];
  const float* gy_w   = (const float*)d_in[12];
  const float* gy_b   = (const float*)d_in[13];
  const float* yy_w   = (const float*)d_in[14];
  const float* yy_b   = (const float*)d_in[15];
  const float* ss_w   = (const float*)d_in[16];
  const float* gs_w   = (const float*)d_in[17];
  const float* gs_b   = (const float*)d_in[18];
  const float* ys_w   = (const float*)d_in[19];
  const float* ys_b   = (const float*)d_in[20];

  float* W = (float*)d_ws;
  unsigned* cnt = (unsigned*)d_ws;
  (void)hipMemsetAsync(d_ws, 0, N_ZERO * sizeof(float), stream);

  // Mmat = ys_w @ yy_w, plus folded constants c1, c2
  {
    dim3 g(H / 64, H4 / 64, 1);
    gemm64<false><<<g, 256, 0, stream>>>(ys_w, yy_w, nullptr, W + O_MMAT, H4, H, V, 0, 0, 0);
  }
  c1c2k<<<H4, 256, 0, stream>>>(ys_w, yy_b, W + O_C1, W + O_C2);

  float* xp = W + O_XP;
  float* hA = W + O_HBA;
  float* hB = W + O_HBB;

  // ---- encoder ----
  {
    dim3 g(H4 / 64, (T_N + 63) / 64, 2);
    gemm64<true><<<g, 256, 0, stream>>>(data, wih0, b0, xp, T_N, H4, DIN,
                                        (size_t)H4 * DIN, H4, (size_t)T_N * H4);
  }
  lstm_scan<<<2 * SWG, STH, 0, stream>>>(whh0, xp, hA, W + O_GBUF, cnt);
  for (int l = 1; l < NLAY; ++l) {
    const float* inb = (l & 1) ? hA : hB;
    float* outb = (l & 1) ? hB : hA;
    dim3 g(H4 / 64, (T_N + 63) / 64, 2);
    gemm64<true><<<g, 256, 0, stream>>>(inb, wihL + (size_t)(l - 1) * 2 * H4 * H2,
                                        bL + (size_t)(l - 1) * 2 * H4, xp, T_N, H4, H2,
                                        (size_t)H4 * H2, H4, (size_t)T_N * H4);
    lstm_scan<<<2 * SWG, STH, 0, stream>>>(whhL + (size_t)(l - 1) * 2 * H4 * H, xp, outb,
                                           W + O_GBUF, cnt + l * 256);
  }
  const float* hfin = hB;  // layer 3 output

  // hproj = hpack @ atth_w^T + atth_b
  {
    dim3 g(H2 / 64, (T_N + 63) / 64, 1);
    gemm64<true><<<g, 256, 0, stream>>>(hfin, atth_w, atth_b, W + O_HPROJ, T_N, H2, H2, 0, 0, 0);
  }

  // ---- decoder ----
  DecArgs da;
  da.atts_w = atts_w; da.attw_w = attw_w;
  da.sy_w = sy_w; da.gy_w = gy_w; da.gy_b = gy_b;
  da.yy_w = yy_w; da.yy_b = yy_b;
  da.gs_b = gs_b; da.ys_b = ys_b;
  da.ss_w = ss_w; da.gs_w = gs_w;
  da.hpack = hfin; da.hproj = W + O_HPROJ; da.Mm = W + O_MMAT; da.c1 = W + O_C1; da.c2 = W + O_C2;
  da.sproj = W + O_SPROJ; da.pden = W + O_PDEN; da.pexp = W + O_PEXP; da.ptv = W + O_PTV;
  da.gvec = W + O_GVEC; da.pre = W + O_PRE; da.abuf = W + O_ABUF; da.pg = W + O_PG;
  da.pti = (int*)(W + O_PTI);
  da.flags = cnt + 1024;
  da.out = (float*)d_out;
  decoder<<<DWG, DTH, 0, stream>>>(da);
}